// Round 2
// baseline (190.522 us; speedup 1.0000x reference)
//
#include <hip/hip_runtime.h>
#include <hip/hip_bf16.h>
#include <math.h>

// R10: barrier-minimal. GEMM B-operands (and gemm_i A) are K-major, so MFMA
// fragments load DIRECTLY from global/L2 (16B contiguous per lane, 64B per
// 4-quad column) -- no LDS staging, no barriers in any GEMM K-loop.
// stage2 conv restaged 128ch x 2 with conv/LN in registers: 34 -> 6 barriers.
// fused_so: 512 blocks x 512 thr (2 blocks/CU), 1 barrier total.

using bf16x8 = __attribute__((ext_vector_type(8))) short;
using f32x4  = __attribute__((ext_vector_type(4))) float;

static __device__ inline unsigned short f2bf(float v) {
  __hip_bfloat16 b = __float2bfloat16(v);
  return *reinterpret_cast<unsigned short*>(&b);
}
static __device__ inline float us2f(unsigned short u) {
  union { unsigned u; float f; } c; c.u = ((unsigned)u) << 16; return c.f;
}

// ---------------- prep (weights transpose->bf16) + x NCHW -> xT [pix][c] ----
__global__ __launch_bounds__(256) void prep_xt_k(
    const float* __restrict__ x,
    const float* __restrict__ inp_w, const float* __restrict__ off_w,
    const float* __restrict__ off_b, const float* __restrict__ mask_w,
    const float* __restrict__ mask_b, const float* __restrict__ out_w,
    __hip_bfloat16* __restrict__ BtI, __hip_bfloat16* __restrict__ BtOM,
    __hip_bfloat16* __restrict__ BtO, float* __restrict__ bOM,
    __hip_bfloat16* __restrict__ xT)
{
  __shared__ float tile[32][65];
  const int b = blockIdx.x, t = threadIdx.x;
  if (b < 1024) {
    if (b < 256) {
      int n = b;
      BtI[n * 256 + t] = __float2bfloat16(inp_w[t * 256 + n]);
    } else if (b < 768) {
      int n = b - 256;
      float v = 0.f;
      if (n < 288) v = off_w[t * 288 + n];
      else if (n < 432) v = mask_w[t * 144 + (n - 288)];
      BtOM[n * 256 + t] = __float2bfloat16(v);
      if (b == 256) {
        for (int idx = t; idx < 512; idx += 256) {
          float bv = (idx < 288) ? off_b[idx] : ((idx < 432) ? mask_b[idx - 288] : 0.f);
          bOM[idx] = bv;
        }
      }
    } else {
      int n = b - 768;
      BtO[n * 256 + t] = __float2bfloat16(out_w[t * 256 + n]);
    }
    return;
  }
  const int i = b - 1024;                 // 0..2047
  const int hw0 = (i & 63) * 64, c0 = ((i >> 6) & 7) * 32, n4 = i >> 9;
  #pragma unroll
  for (int r = 0; r < 8; ++r) {
    int idx = t + r * 256;
    int cl = idx >> 6, wl = idx & 63;
    tile[cl][wl] = x[(size_t)n4 * 1048576 + (size_t)(c0 + cl) * 4096 + hw0 + wl];
  }
  __syncthreads();
  #pragma unroll
  for (int r = 0; r < 2; ++r) {
    int idx = t + r * 256;                // 512 tasks = 64 pix * 8 cquads
    int pixl = idx >> 3, cq = idx & 7;
    unsigned short b0 = f2bf(tile[cq * 4 + 0][pixl]);
    unsigned short b1 = f2bf(tile[cq * 4 + 1][pixl]);
    unsigned short b2 = f2bf(tile[cq * 4 + 2][pixl]);
    unsigned short b3 = f2bf(tile[cq * 4 + 3][pixl]);
    uint2 u;
    u.x = (unsigned)b0 | ((unsigned)b1 << 16);
    u.y = (unsigned)b2 | ((unsigned)b3 << 16);
    *(uint2*)&xT[((size_t)n4 * 4096 + hw0 + pixl) * 256 + c0 + cq * 4] = u;
  }
}

// ---------------- K2: stage2 (dwconv+LN+GELU+OM GEMM) ∥ input-proj GEMM -----
// blocks 0..255  : stage2 row (64 px), 16 waves, 6 barriers total
// blocks 256..511: gemm_i, 4x 64x64 tiles, zero LDS, zero barriers
__global__ __launch_bounds__(1024) void stage2_gi_k(
    const __hip_bfloat16* __restrict__ xT,
    const float* __restrict__ dw_w, const float* __restrict__ dw_b,
    const float* __restrict__ ln_g, const float* __restrict__ ln_b,
    const __hip_bfloat16* __restrict__ BtOM, const float* __restrict__ bOM,
    __hip_bfloat16* __restrict__ om,
    const __hip_bfloat16* __restrict__ BtI, const float* __restrict__ inp_b,
    __hip_bfloat16* __restrict__ xpu)
{
  __shared__ __align__(16) char smem[65024];
  const int bid = blockIdx.x;

  if (bid >= 256) {
    // -------- input-proj GEMM: xT @ BtI -> xpu. Direct frag loads. --------
    const int sb = threadIdx.x >> 8;         // sub-block 0..3
    const int t = threadIdx.x & 255;
    const int tile = (bid - 256) * 4 + sb;   // 0..1023
    const int n0 = (tile & 3) * 64;
    const size_t m0 = (size_t)(tile >> 2) * 64;
    const int lane = t & 63, quad = lane >> 4, lr = lane & 15;
    const int wave = t >> 6, wm = wave >> 1, wn = wave & 1;

    f32x4 acc[2][2];
    #pragma unroll
    for (int i = 0; i < 2; ++i)
      #pragma unroll
      for (int j = 0; j < 2; ++j)
        acc[i][j] = (f32x4){0.f, 0.f, 0.f, 0.f};

    const __hip_bfloat16* ap = xT + (m0 + wm * 32 + lr) * 256 + quad * 8;
    const __hip_bfloat16* bp = BtI + (size_t)(n0 + wn * 32 + lr) * 256 + quad * 8;
    #pragma unroll 2
    for (int kt = 0; kt < 256; kt += 32) {
      bf16x8 a0 = *(const bf16x8*)(ap + kt);
      bf16x8 a1 = *(const bf16x8*)(ap + 4096 + kt);     // +16 rows
      bf16x8 b0 = *(const bf16x8*)(bp + kt);
      bf16x8 b1 = *(const bf16x8*)(bp + 4096 + kt);
      acc[0][0] = __builtin_amdgcn_mfma_f32_16x16x32_bf16(a0, b0, acc[0][0], 0, 0, 0);
      acc[0][1] = __builtin_amdgcn_mfma_f32_16x16x32_bf16(a0, b1, acc[0][1], 0, 0, 0);
      acc[1][0] = __builtin_amdgcn_mfma_f32_16x16x32_bf16(a1, b0, acc[1][0], 0, 0, 0);
      acc[1][1] = __builtin_amdgcn_mfma_f32_16x16x32_bf16(a1, b1, acc[1][1], 0, 0, 0);
    }
    #pragma unroll
    for (int mi = 0; mi < 2; ++mi) {
      #pragma unroll
      for (int ni = 0; ni < 2; ++ni) {
        int col = n0 + wn * 32 + ni * 16 + lr;
        float bv = inp_b[col];
        #pragma unroll
        for (int reg = 0; reg < 4; ++reg) {
          size_t m = m0 + wm * 32 + mi * 16 + quad * 4 + reg;
          xpu[m * 256 + col] = __float2bfloat16(acc[mi][ni][reg] + bv);
        }
      }
    }
    return;
  }

  // -------- stage2 role --------
  unsigned short* x1t = (unsigned short*)smem;            // [64][264] 33792 B (GEMM phase)
  unsigned short* xs  = (unsigned short*)smem;            // [192][136] 52224 B (conv phase, aliases x1t)
  float* psq  = (float*)(smem + 52224);                   // ps[1024]|pq[1024] 8192 B
  float* wgt  = (float*)(smem + 60416);                   // [9][128] 4608 B
  float* murs = (float*)(smem + 60416);                   // aliases wgt after conv

  const int blk = ((bid & 7) << 5) | (bid >> 3);          // bijective XCD swizzle
  const int n4 = blk >> 6, h = blk & 63;
  const int t = threadIdx.x;
  const int w = t & 63, q = t >> 6;                       // pixel w, ch-group q (0..15)

  float av[16];
  float s1 = 0.f, s2 = 0.f;

  #pragma unroll
  for (int half = 0; half < 2; ++half) {
    const int ch0 = half * 128;
    if (half) __syncthreads();              // conv of half 0 done before restage
    #pragma unroll
    for (int it = 0; it < 3; ++it) {        // stage xs: 3 rows x 64 px x 128 ch
      int i = t + it * 1024;
      int rp = i >> 4, cq = i & 15;
      int r = rp >> 6, px = rp & 63;
      int hh = h + r - 1;
      uint4 v = {0, 0, 0, 0};
      if ((unsigned)hh < 64u)
        v = *(const uint4*)(xT + ((size_t)n4 * 4096 + (size_t)hh * 64 + px) * 256 + ch0 + cq * 8);
      *(uint4*)&xs[rp * 136 + cq * 8] = v;
    }
    for (int idx = t; idx < 1152; idx += 1024) {  // weights [9][128]
      int p = idx >> 7, lc = idx & 127;
      wgt[p * 128 + lc] = dw_w[(ch0 + lc) * 9 + p];
    }
    __syncthreads();
    #pragma unroll
    for (int ck = 0; ck < 4; ++ck) {        // conv: 2 ch per thread per chunk
      int cl = ck * 32 + 2 * q;
      int c = ch0 + cl;
      float a0 = dw_b[c], a1 = dw_b[c + 1];
      #pragma unroll
      for (int p = 0; p < 9; ++p) {
        int dh = p / 3, dwd = p % 3 - 1;
        int ww = w + dwd;
        if ((unsigned)ww < 64u) {
          unsigned xv = *(const unsigned*)&xs[(dh * 64 + ww) * 136 + cl];
          float wa = wgt[p * 128 + cl], wb = wgt[p * 128 + cl + 1];
          a0 = fmaf(us2f((unsigned short)(xv & 0xffff)), wa, a0);
          a1 = fmaf(us2f((unsigned short)(xv >> 16)), wb, a1);
        }
      }
      s1 += a0 + a1;
      s2 = fmaf(a0, a0, fmaf(a1, a1, s2));
      av[(half * 4 + ck) * 2] = a0;
      av[(half * 4 + ck) * 2 + 1] = a1;
    }
  }

  psq[q * 64 + w] = s1;
  psq[1024 + q * 64 + w] = s2;
  __syncthreads();
  if (t < 64) {
    float a = 0.f, b = 0.f;
    #pragma unroll
    for (int j = 0; j < 16; ++j) { a += psq[j * 64 + t]; b += psq[1024 + j * 64 + t]; }
    float mu = a * (1.f / 256.f);
    murs[t] = mu;
    murs[64 + t] = rsqrtf(b * (1.f / 256.f) - mu * mu + 1e-5f);
  }
  __syncthreads();
  {                                          // LN + GELU on fp32 regs -> x1t bf16
    float mu = murs[w], rs = murs[64 + w];
    #pragma unroll
    for (int ck = 0; ck < 8; ++ck) {
      int c = ck * 32 + 2 * q;
      float y0 = fmaf((av[ck * 2] - mu) * rs, ln_g[c], ln_b[c]);
      float y1 = fmaf((av[ck * 2 + 1] - mu) * rs, ln_g[c + 1], ln_b[c + 1]);
      float g0 = 0.5f * y0 * (1.f + erff(y0 * 0.70710678f));
      float g1 = 0.5f * y1 * (1.f + erff(y1 * 0.70710678f));
      *(unsigned*)&x1t[w * 264 + c] = (unsigned)f2bf(g0) | ((unsigned)f2bf(g1) << 16);
    }
  }
  __syncthreads();

  // OM GEMM: M=64, N=448 (432 valid), K=256. 16 waves = 4m x 4n.
  // B fragments direct from global (K-major); A from x1t LDS. Zero barriers.
  const int wave = t >> 6, lane = t & 63;
  const int quad = lane >> 4, lr = lane & 15;
  const int wm = wave >> 2, wn = wave & 3;
  f32x4 acc[7];
  #pragma unroll
  for (int i = 0; i < 7; ++i) acc[i] = (f32x4){0.f, 0.f, 0.f, 0.f};

  const __hip_bfloat16* bp = BtOM + (size_t)(wn * 112 + lr) * 256 + quad * 8;
  const unsigned short* abase = &x1t[(wm * 16 + lr) * 264 + quad * 8];
  #pragma unroll 2
  for (int kt = 0; kt < 256; kt += 32) {
    bf16x8 af = *(const bf16x8*)(abase + kt);
    bf16x8 bfr[7];
    #pragma unroll
    for (int ni = 0; ni < 7; ++ni)
      bfr[ni] = *(const bf16x8*)(bp + (size_t)ni * 4096 + kt);
    #pragma unroll
    for (int ni = 0; ni < 7; ++ni)
      acc[ni] = __builtin_amdgcn_mfma_f32_16x16x32_bf16(af, bfr[ni], acc[ni], 0, 0, 0);
  }

  const size_t pix0 = (size_t)n4 * 4096 + (size_t)h * 64;
  #pragma unroll
  for (int ni = 0; ni < 7; ++ni) {
    int col = wn * 112 + ni * 16 + lr;
    if (col < 432) {
      float bv = bOM[col];
      #pragma unroll
      for (int reg = 0; reg < 4; ++reg) {
        int m = wm * 16 + quad * 4 + reg;
        om[(pix0 + m) * 448 + col] = __float2bfloat16(acc[ni][reg] + bv);
      }
    }
  }
}

// ---------------- K3: sampling -> LDS tile -> output-proj GEMM -> fp32 NCHW -
// 512 blocks x 512 thr (32 px each, 2 blocks/CU). 1 barrier total.
__global__ __launch_bounds__(512) void fused_so_k(
    const __hip_bfloat16* __restrict__ xpu, const __hip_bfloat16* __restrict__ om,
    const __hip_bfloat16* __restrict__ BtO, const float* __restrict__ out_b,
    float* __restrict__ out)
{
  __shared__ __align__(16) unsigned short st[32 * 264];   // 16896 B

  const int bid = blockIdx.x;                             // 512
  const int swz = ((bid & 7) << 6) | (bid >> 3);          // bijective XCD swizzle
  const int pix0 = swz << 5;                              // 32 consecutive pixels
  const int t = threadIdx.x;

  // ---- sampling: thread = (pixel pl 0..31, group g 0..15) ----
  {
    const int pl = t >> 4, g = t & 15;
    const int pix = pix0 + pl;
    const int n4s = pix >> 12;
    const int hw = pix & 4095;
    const int h = hw >> 6, w = hw & 63;
    const unsigned short* omp = (const unsigned short*)om + (size_t)pix * 448;

    float mk[9];
    {
      float mx = -1e30f;
      #pragma unroll
      for (int p = 0; p < 9; ++p) { mk[p] = us2f(omp[288 + g * 9 + p]); mx = fmaxf(mx, mk[p]); }
      float se = 0.f;
      #pragma unroll
      for (int p = 0; p < 9; ++p) { mk[p] = __expf(mk[p] - mx); se += mk[p]; }
      float inv = 1.f / se;
      #pragma unroll
      for (int p = 0; p < 9; ++p) mk[p] *= inv;
    }

    const __hip_bfloat16* xpg = xpu + (g << 4);
    float ax[16];
    #pragma unroll
    for (int i = 0; i < 16; ++i) ax[i] = 0.f;

    auto corner = [&](int iy, int ix, float wt) {
      if ((unsigned)(iy - 1) >= 64u || (unsigned)(ix - 1) >= 64u) return;
      const __hip_bfloat16* src =
          xpg + ((size_t)((n4s << 12) + (iy - 1) * 64 + (ix - 1)) << 8);
      uint4 u0 = *(const uint4*)src;
      uint4 u1 = *(const uint4*)(src + 8);
      const unsigned uu[8] = {u0.x, u0.y, u0.z, u0.w, u1.x, u1.y, u1.z, u1.w};
      #pragma unroll
      for (int i = 0; i < 8; ++i) {
        float lo = us2f((unsigned short)(uu[i] & 0xffff));
        float hi = us2f((unsigned short)(uu[i] >> 16));
        ax[2 * i + 0] = fmaf(wt, lo, ax[2 * i + 0]);
        ax[2 * i + 1] = fmaf(wt, hi, ax[2 * i + 1]);
      }
    };

    #pragma unroll
    for (int p = 0; p < 9; ++p) {
      float ox = us2f(omp[g * 18 + 2 * p]), oy = us2f(omp[g * 18 + 2 * p + 1]);
      float px = (float)(w + p / 3) + ox;
      float py = (float)(h + p % 3) + oy;
      float xf = floorf(px), yf = floorf(py);
      float wx = px - xf, wy = py - yf;
      int ix = (int)xf, iy = (int)yf;
      float m = mk[p];
      corner(iy,     ix,     (1.f - wy) * (1.f - wx) * m);
      corner(iy,     ix + 1, (1.f - wy) * wx * m);
      corner(iy + 1, ix,     wy * (1.f - wx) * m);
      corner(iy + 1, ix + 1, wy * wx * m);
    }

    unsigned short ub[16];
    #pragma unroll
    for (int i = 0; i < 16; ++i) ub[i] = f2bf(ax[i]);
    uint4 u0, u1;
    u0.x = (unsigned)ub[0] | ((unsigned)ub[1] << 16);
    u0.y = (unsigned)ub[2] | ((unsigned)ub[3] << 16);
    u0.z = (unsigned)ub[4] | ((unsigned)ub[5] << 16);
    u0.w = (unsigned)ub[6] | ((unsigned)ub[7] << 16);
    u1.x = (unsigned)ub[8] | ((unsigned)ub[9] << 16);
    u1.y = (unsigned)ub[10] | ((unsigned)ub[11] << 16);
    u1.z = (unsigned)ub[12] | ((unsigned)ub[13] << 16);
    u1.w = (unsigned)ub[14] | ((unsigned)ub[15] << 16);
    *(uint4*)&st[pl * 264 + g * 16] = u0;
    *(uint4*)&st[pl * 264 + g * 16 + 8] = u1;
  }
  __syncthreads();

  // ---- out-proj GEMM: st(32x256) @ BtO^T. 8 waves = 2m x 4n. No barriers. ----
  const int wave = t >> 6, lane = t & 63;
  const int quad = lane >> 4, lr = lane & 15;
  const int wm = wave >> 2, wn = wave & 3;
  f32x4 acc[4];
  #pragma unroll
  for (int i = 0; i < 4; ++i) acc[i] = (f32x4){0.f, 0.f, 0.f, 0.f};

  const __hip_bfloat16* bp = BtO + (size_t)(wn * 64 + lr) * 256 + quad * 8;
  const unsigned short* abase = &st[(wm * 16 + lr) * 264 + quad * 8];
  #pragma unroll 2
  for (int kt = 0; kt < 256; kt += 32) {
    bf16x8 af = *(const bf16x8*)(abase + kt);
    #pragma unroll
    for (int ni = 0; ni < 4; ++ni) {
      bf16x8 bf = *(const bf16x8*)(bp + (size_t)ni * 4096 + kt);
      acc[ni] = __builtin_amdgcn_mfma_f32_16x16x32_bf16(af, bf, acc[ni], 0, 0, 0);
    }
  }

  // fp32 NCHW stores: one wave's 4 quads cover each full 64-B line
  const int n4 = pix0 >> 12, hw0 = pix0 & 4095;
  #pragma unroll
  for (int ni = 0; ni < 4; ++ni) {
    int col = wn * 64 + ni * 16 + lr;
    float bv = out_b[col];
    float4 v;
    v.x = acc[ni][0] + bv; v.y = acc[ni][1] + bv;
    v.z = acc[ni][2] + bv; v.w = acc[ni][3] + bv;
    *(float4*)&out[(size_t)(n4 * 256 + col) * 4096 + hw0 + wm * 16 + quad * 4] = v;
  }
}

extern "C" void kernel_launch(void* const* d_in, const int* in_sizes, int n_in,
                              void* d_out, int out_size, void* d_ws, size_t ws_size,
                              hipStream_t stream) {
  const float* x      = (const float*)d_in[0];
  const float* dw_w   = (const float*)d_in[1];
  const float* dw_b   = (const float*)d_in[2];
  const float* ln_g   = (const float*)d_in[3];
  const float* ln_b   = (const float*)d_in[4];
  const float* off_w  = (const float*)d_in[5];
  const float* off_b  = (const float*)d_in[6];
  const float* mask_w = (const float*)d_in[7];
  const float* mask_b = (const float*)d_in[8];
  const float* inp_w  = (const float*)d_in[9];
  const float* inp_b  = (const float*)d_in[10];
  const float* out_w  = (const float*)d_in[11];
  const float* out_b  = (const float*)d_in[12];
  float* out = (float*)d_out;

  char* w0 = (char*)d_ws;
  __hip_bfloat16* xpu  = (__hip_bfloat16*)(w0);               //  8,388,608 B
  __hip_bfloat16* xT   = (__hip_bfloat16*)(w0 + 8388608);     //  8,388,608 B
  __hip_bfloat16* om   = (__hip_bfloat16*)(w0 + 16777216);    // 14,680,064 B
  __hip_bfloat16* BtI  = (__hip_bfloat16*)(w0 + 31457280);    //    131,072 B
  __hip_bfloat16* BtOM = (__hip_bfloat16*)(w0 + 31588352);    //    262,144 B
  __hip_bfloat16* BtO  = (__hip_bfloat16*)(w0 + 31850496);    //    131,072 B
  float*          bOM  = (float*)(w0 + 31981568);             //      2,048 B
  if (ws_size < 31983616) return;

  prep_xt_k<<<3072, 256, 0, stream>>>(x, inp_w, off_w, off_b, mask_w, mask_b,
                                      out_w, BtI, BtOM, BtO, bOM, xT);
  stage2_gi_k<<<512, 1024, 0, stream>>>(xT, dw_w, dw_b, ln_g, ln_b, BtOM, bOM, om,
                                        BtI, inp_b, xpu);
  fused_so_k<<<512, 512, 0, stream>>>(xpu, om, BtO, out_b, out);
}

// Round 3
// 157.589 us; speedup vs baseline: 1.2090x; 1.2090x over previous
//
#include <hip/hip_runtime.h>
#include <hip/hip_bf16.h>
#include <math.h>

// R11: R9 structure (LDS-staged GEMMs, measured better than R10 direct loads)
// + conv rebuilt: reads x (fp32 NCHW) directly from global -- wave = one row,
// w-halo via __shfl, h-halo via uniform-branch row loads. Conv: 0 barriers,
// 0 LDS, 0 bank conflicts. stage2 barriers 34 -> ~20.

using bf16x8 = __attribute__((ext_vector_type(8))) short;
using f32x4  = __attribute__((ext_vector_type(4))) float;

#define GLOBAL_AS __attribute__((address_space(1)))
#define LDS_AS    __attribute__((address_space(3)))

static __device__ inline void g2lds16(const void* g, void* l) {
  __builtin_amdgcn_global_load_lds((const GLOBAL_AS int*)g, (LDS_AS int*)l, 16, 0, 0);
}
static __device__ inline unsigned short f2bf(float v) {
  __hip_bfloat16 b = __float2bfloat16(v);
  return *reinterpret_cast<unsigned short*>(&b);
}
static __device__ inline float us2f(unsigned short u) {
  union { unsigned u; float f; } c; c.u = ((unsigned)u) << 16; return c.f;
}

// ---------------- prep (weights transpose->bf16) + x NCHW -> xT [pix][c] ----
__global__ __launch_bounds__(256) void prep_xt_k(
    const float* __restrict__ x,
    const float* __restrict__ inp_w, const float* __restrict__ off_w,
    const float* __restrict__ off_b, const float* __restrict__ mask_w,
    const float* __restrict__ mask_b, const float* __restrict__ out_w,
    __hip_bfloat16* __restrict__ BtI, __hip_bfloat16* __restrict__ BtOM,
    __hip_bfloat16* __restrict__ BtO, float* __restrict__ bOM,
    __hip_bfloat16* __restrict__ xT)
{
  __shared__ float tile[32][65];
  const int b = blockIdx.x, t = threadIdx.x;
  if (b < 1024) {
    if (b < 256) {
      int n = b;
      BtI[n * 256 + t] = __float2bfloat16(inp_w[t * 256 + n]);
    } else if (b < 768) {
      int n = b - 256;
      float v = 0.f;
      if (n < 288) v = off_w[t * 288 + n];
      else if (n < 432) v = mask_w[t * 144 + (n - 288)];
      BtOM[n * 256 + t] = __float2bfloat16(v);
      if (b == 256) {
        for (int idx = t; idx < 512; idx += 256) {
          float bv = (idx < 288) ? off_b[idx] : ((idx < 432) ? mask_b[idx - 288] : 0.f);
          bOM[idx] = bv;
        }
      }
    } else {
      int n = b - 768;
      BtO[n * 256 + t] = __float2bfloat16(out_w[t * 256 + n]);
    }
    return;
  }
  const int i = b - 1024;                 // 0..2047
  const int hw0 = (i & 63) * 64, c0 = ((i >> 6) & 7) * 32, n4 = i >> 9;
  #pragma unroll
  for (int r = 0; r < 8; ++r) {
    int idx = t + r * 256;
    int cl = idx >> 6, wl = idx & 63;
    tile[cl][wl] = x[(size_t)n4 * 1048576 + (size_t)(c0 + cl) * 4096 + hw0 + wl];
  }
  __syncthreads();
  #pragma unroll
  for (int r = 0; r < 2; ++r) {
    int idx = t + r * 256;                // 512 tasks = 64 pix * 8 cquads
    int pixl = idx >> 3, cq = idx & 7;
    unsigned short b0 = f2bf(tile[cq * 4 + 0][pixl]);
    unsigned short b1 = f2bf(tile[cq * 4 + 1][pixl]);
    unsigned short b2 = f2bf(tile[cq * 4 + 2][pixl]);
    unsigned short b3 = f2bf(tile[cq * 4 + 3][pixl]);
    uint2 u;
    u.x = (unsigned)b0 | ((unsigned)b1 << 16);
    u.y = (unsigned)b2 | ((unsigned)b3 << 16);
    *(uint2*)&xT[((size_t)n4 * 4096 + hw0 + pixl) * 256 + c0 + cq * 4] = u;
  }
}

// ---------------- 64x64 MFMA GEMM core (LDS-staged, R9) ---------------------
struct G64 {
  f32x4 acc[2][2];
  int lane, quad, lr, wm, wn;
};

static __device__ inline void g64_loop(
    G64& g, const __hip_bfloat16* __restrict__ A,
    const __hip_bfloat16* __restrict__ Bt, size_t m0, int n0,
    short* As, short* Bs, int t)
{
  #pragma unroll
  for (int i = 0; i < 2; ++i)
    #pragma unroll
    for (int j = 0; j < 2; ++j)
      g.acc[i][j] = (f32x4){0.f, 0.f, 0.f, 0.f};
  const int row = t >> 2, kq = t & 3;
  for (int kt = 0; kt < 256; kt += 32) {
    g2lds16(A + (m0 + row) * 256 + kt + kq * 8, (char*)As + t * 16);
    g2lds16(Bt + (size_t)(n0 + row) * 256 + kt + kq * 8, (char*)Bs + t * 16);
    __syncthreads();
    bf16x8 bfv[2];
    #pragma unroll
    for (int ni = 0; ni < 2; ++ni)
      bfv[ni] = *(const bf16x8*)&Bs[(g.wn * 32 + ni * 16 + g.lr) * 32 + g.quad * 8];
    #pragma unroll
    for (int mi = 0; mi < 2; ++mi) {
      bf16x8 af = *(const bf16x8*)&As[(g.wm * 32 + mi * 16 + g.lr) * 32 + g.quad * 8];
      #pragma unroll
      for (int ni = 0; ni < 2; ++ni)
        g.acc[mi][ni] = __builtin_amdgcn_mfma_f32_16x16x32_bf16(af, bfv[ni], g.acc[mi][ni], 0, 0, 0);
    }
    __syncthreads();
  }
}

// ---------------- K2: stage2 (dwconv+LN+GELU+OM GEMM) ∥ input-proj GEMM -----
// blocks 0..255  : stage2 row (64 px), 16 waves; conv direct from x via shfl
// blocks 256..511: gemm_i, 4x 64x64 tiles (R9 LDS-staged)
__global__ __launch_bounds__(1024) void stage2_gi_k(
    const float* __restrict__ x,
    const __hip_bfloat16* __restrict__ xT,
    const float* __restrict__ dw_w, const float* __restrict__ dw_b,
    const float* __restrict__ ln_g, const float* __restrict__ ln_b,
    const __hip_bfloat16* __restrict__ BtOM, const float* __restrict__ bOM,
    __hip_bfloat16* __restrict__ om,
    const __hip_bfloat16* __restrict__ BtI, const float* __restrict__ inp_b,
    __hip_bfloat16* __restrict__ xpu)
{
  __shared__ __align__(16) char smem[62464];
  const int bid = blockIdx.x;

  if (bid >= 256) {
    // -------- input-proj GEMM role: xT @ BtI -> xpu (R9, LDS-staged) --------
    const int sb = threadIdx.x >> 8;         // sub-block 0..3
    const int t = threadIdx.x & 255;
    const int tile = (bid - 256) * 4 + sb;   // 0..1023
    const int n0 = (tile & 3) * 64;
    const size_t m0 = (size_t)(tile >> 2) * 64;
    short* As = (short*)(smem + sb * 8192);
    short* Bs = (short*)(smem + sb * 8192 + 4096);

    G64 g;
    g.lane = t & 63; g.quad = g.lane >> 4; g.lr = g.lane & 15;
    int wave = t >> 6;
    g.wm = wave >> 1; g.wn = wave & 1;
    g64_loop(g, xT, BtI, m0, n0, As, Bs, t);

    #pragma unroll
    for (int mi = 0; mi < 2; ++mi) {
      #pragma unroll
      for (int ni = 0; ni < 2; ++ni) {
        int col = n0 + g.wn * 32 + ni * 16 + g.lr;
        float bv = inp_b[col];
        #pragma unroll
        for (int reg = 0; reg < 4; ++reg) {
          size_t m = m0 + g.wm * 32 + mi * 16 + g.quad * 4 + reg;
          xpu[m * 256 + col] = __float2bfloat16(g.acc[mi][ni][reg] + bv);
        }
      }
    }
    return;
  }

  // -------- stage2 role --------
  unsigned short* x1t = (unsigned short*)smem;            // [64][264] 33792 B (persists into GEMM)
  float* psq  = (float*)(smem + 33792);                   // ps[1024]|pq[1024] 8192 B
  float* murs = (float*)(smem + 41984);                   // mu[64]|rs[64] 512 B
  short* Bs   = (short*)(smem + 33792);                   // GEMM phase: [448][32] 28672 B (aliases psq/murs)

  const int blk = ((bid & 7) << 5) | (bid >> 3);          // bijective XCD swizzle
  const int n4 = blk >> 6, h = blk & 63;
  const int t = threadIdx.x;
  const int w = t & 63, q = t >> 6;                       // lane = pixel w; wave = ch-group q

  // ---- depthwise 3x3 conv, direct from x (fp32 NCHW), halo via shfl ----
  const float* xb = x + (size_t)n4 * 1048576;             // [256][64][64]
  const bool hm = (h > 0), hp = (h < 63);
  float av[16];
  float s1 = 0.f, s2 = 0.f;

  #pragma unroll 2
  for (int j = 0; j < 8; ++j) {
    #pragma unroll
    for (int u = 0; u < 2; ++u) {
      const int c = q * 16 + 2 * j + u;
      const float* xc = xb + (size_t)c * 4096 + h * 64 + w;
      float v0 = hm ? xc[-64] : 0.f;
      float v1 = xc[0];
      float v2 = hp ? xc[64] : 0.f;
      const float* wp = dw_w + c * 9;                     // wave-uniform (L1 broadcast)
      float a = dw_b[c];
      float vr0 = v0, vr1 = v1, vr2 = v2;
      #pragma unroll
      for (int dh = 0; dh < 3; ++dh) {
        float v = (dh == 0) ? vr0 : (dh == 1) ? vr1 : vr2;
        float vm = __shfl(v, w - 1, 64);
        float vp = __shfl(v, w + 1, 64);
        if (w == 0)  vm = 0.f;
        if (w == 63) vp = 0.f;
        a = fmaf(vm, wp[dh * 3 + 0], a);
        a = fmaf(v,  wp[dh * 3 + 1], a);
        a = fmaf(vp, wp[dh * 3 + 2], a);
      }
      s1 += a;
      s2 = fmaf(a, a, s2);
      av[2 * j + u] = a;
    }
  }

  psq[q * 64 + w] = s1;
  psq[1024 + q * 64 + w] = s2;
  __syncthreads();
  if (t < 64) {
    float a = 0.f, b = 0.f;
    #pragma unroll
    for (int j = 0; j < 16; ++j) { a += psq[j * 64 + t]; b += psq[1024 + j * 64 + t]; }
    float mu = a * (1.f / 256.f);
    murs[t] = mu;
    murs[64 + t] = rsqrtf(b * (1.f / 256.f) - mu * mu + 1e-5f);
  }
  __syncthreads();
  {                                          // LN + GELU on fp32 regs -> x1t bf16
    float mu = murs[w], rs = murs[64 + w];
    #pragma unroll
    for (int j = 0; j < 8; ++j) {
      int c = q * 16 + 2 * j;
      float y0 = fmaf((av[2 * j] - mu) * rs, ln_g[c], ln_b[c]);
      float y1 = fmaf((av[2 * j + 1] - mu) * rs, ln_g[c + 1], ln_b[c + 1]);
      float g0 = 0.5f * y0 * (1.f + erff(y0 * 0.70710678f));
      float g1 = 0.5f * y1 * (1.f + erff(y1 * 0.70710678f));
      *(unsigned*)&x1t[w * 264 + c] = (unsigned)f2bf(g0) | ((unsigned)f2bf(g1) << 16);
    }
  }
  __syncthreads();                           // x1t done; psq/murs dead (Bs aliases)

  // ---- OM GEMM: M=64, N=448 (432 valid), K=256. 16 waves = 4m x 4n. ----
  const int wave = t >> 6, lane = t & 63;
  const int quad = lane >> 4, lr = lane & 15;
  const int wm = wave >> 2, wn = wave & 3;
  f32x4 acc[7];
  #pragma unroll
  for (int i = 0; i < 7; ++i) acc[i] = (f32x4){0.f, 0.f, 0.f, 0.f};

  for (int kt = 0; kt < 256; kt += 32) {
    __syncthreads();                         // Bs reads from prev iter done
    {
      int col = t >> 2, kq = t & 3;
      g2lds16(BtOM + (size_t)col * 256 + kt + kq * 8, (char*)Bs + t * 16);
      int jj = t + 1024;
      if (jj < 1792) {
        col = jj >> 2; kq = jj & 3;
        g2lds16(BtOM + (size_t)col * 256 + kt + kq * 8, (char*)Bs + jj * 16);
      }
    }
    __syncthreads();
    bf16x8 af = *(const bf16x8*)&x1t[(wm * 16 + lr) * 264 + kt + quad * 8];
    #pragma unroll
    for (int ni = 0; ni < 7; ++ni) {
      bf16x8 bf = *(const bf16x8*)&Bs[(wn * 112 + ni * 16 + lr) * 32 + quad * 8];
      acc[ni] = __builtin_amdgcn_mfma_f32_16x16x32_bf16(af, bf, acc[ni], 0, 0, 0);
    }
  }

  const size_t pix0 = (size_t)n4 * 4096 + (size_t)h * 64;
  #pragma unroll
  for (int ni = 0; ni < 7; ++ni) {
    int col = wn * 112 + ni * 16 + lr;
    if (col < 432) {
      float bv = bOM[col];
      #pragma unroll
      for (int reg = 0; reg < 4; ++reg) {
        int m = wm * 16 + quad * 4 + reg;
        om[(pix0 + m) * 448 + col] = __float2bfloat16(acc[ni][reg] + bv);
      }
    }
  }
}

// ---------------- K3: sampling -> LDS tile -> output-proj GEMM -> fp32 NCHW -
// block = 64 pixels (one image row), 1024 threads (R9 version).
__global__ __launch_bounds__(1024) void fused_so_k(
    const __hip_bfloat16* __restrict__ xpu, const __hip_bfloat16* __restrict__ om,
    const __hip_bfloat16* __restrict__ BtO, const float* __restrict__ out_b,
    float* __restrict__ out)
{
  __shared__ __align__(16) char smem[50176];
  unsigned short* st = (unsigned short*)smem;          // samp tile [64][264] 33792 B
  short* Bs = (short*)(smem + 33792);                  // B-stage [256][32] 16384 B

  const int bid = blockIdx.x;                          // 256
  const int swz = ((bid & 7) << 5) | (bid >> 3);       // bijective XCD swizzle
  const int pix0 = swz << 6;                           // 64 consecutive pixels
  const int t = threadIdx.x;

  // ---- sampling: thread = (pixel pl, group g) ----
  {
    const int pl = t >> 4, g = t & 15;
    const int pix = pix0 + pl;
    const int n4s = pix >> 12;
    const int hw = pix & 4095;
    const int h = hw >> 6, w = hw & 63;
    const unsigned short* omp = (const unsigned short*)om + (size_t)pix * 448;

    float mk[9];
    {
      float mx = -1e30f;
      #pragma unroll
      for (int p = 0; p < 9; ++p) { mk[p] = us2f(omp[288 + g * 9 + p]); mx = fmaxf(mx, mk[p]); }
      float se = 0.f;
      #pragma unroll
      for (int p = 0; p < 9; ++p) { mk[p] = __expf(mk[p] - mx); se += mk[p]; }
      float inv = 1.f / se;
      #pragma unroll
      for (int p = 0; p < 9; ++p) mk[p] *= inv;
    }

    const __hip_bfloat16* xpg = xpu + (g << 4);
    float ax[16];
    #pragma unroll
    for (int i = 0; i < 16; ++i) ax[i] = 0.f;

    auto corner = [&](int iy, int ix, float wt) {
      if ((unsigned)(iy - 1) >= 64u || (unsigned)(ix - 1) >= 64u) return;
      const __hip_bfloat16* src =
          xpg + ((size_t)((n4s << 12) + (iy - 1) * 64 + (ix - 1)) << 8);
      uint4 u0 = *(const uint4*)src;
      uint4 u1 = *(const uint4*)(src + 8);
      const unsigned uu[8] = {u0.x, u0.y, u0.z, u0.w, u1.x, u1.y, u1.z, u1.w};
      #pragma unroll
      for (int i = 0; i < 8; ++i) {
        float lo = us2f((unsigned short)(uu[i] & 0xffff));
        float hi = us2f((unsigned short)(uu[i] >> 16));
        ax[2 * i + 0] = fmaf(wt, lo, ax[2 * i + 0]);
        ax[2 * i + 1] = fmaf(wt, hi, ax[2 * i + 1]);
      }
    };

    #pragma unroll
    for (int p = 0; p < 9; ++p) {
      float ox = us2f(omp[g * 18 + 2 * p]), oy = us2f(omp[g * 18 + 2 * p + 1]);
      float px = (float)(w + p / 3) + ox;
      float py = (float)(h + p % 3) + oy;
      float xf = floorf(px), yf = floorf(py);
      float wx = px - xf, wy = py - yf;
      int ix = (int)xf, iy = (int)yf;
      float m = mk[p];
      corner(iy,     ix,     (1.f - wy) * (1.f - wx) * m);
      corner(iy,     ix + 1, (1.f - wy) * wx * m);
      corner(iy + 1, ix,     wy * (1.f - wx) * m);
      corner(iy + 1, ix + 1, wy * wx * m);
    }

    unsigned short ub[16];
    #pragma unroll
    for (int i = 0; i < 16; ++i) ub[i] = f2bf(ax[i]);
    uint4 u0, u1;
    u0.x = (unsigned)ub[0] | ((unsigned)ub[1] << 16);
    u0.y = (unsigned)ub[2] | ((unsigned)ub[3] << 16);
    u0.z = (unsigned)ub[4] | ((unsigned)ub[5] << 16);
    u0.w = (unsigned)ub[6] | ((unsigned)ub[7] << 16);
    u1.x = (unsigned)ub[8] | ((unsigned)ub[9] << 16);
    u1.y = (unsigned)ub[10] | ((unsigned)ub[11] << 16);
    u1.z = (unsigned)ub[12] | ((unsigned)ub[13] << 16);
    u1.w = (unsigned)ub[14] | ((unsigned)ub[15] << 16);
    *(uint4*)&st[pl * 264 + g * 16] = u0;
    *(uint4*)&st[pl * 264 + g * 16 + 8] = u1;
  }

  // ---- out-proj GEMM: st(64x256) @ BtO^T -> out, 16 waves = 4m x 4n ----
  const int wave = t >> 6, lane = t & 63;
  const int quad = lane >> 4, lr = lane & 15;
  const int wm = wave >> 2, wn = wave & 3;
  f32x4 acc[4];
  #pragma unroll
  for (int i = 0; i < 4; ++i) acc[i] = (f32x4){0.f, 0.f, 0.f, 0.f};

  for (int kt = 0; kt < 256; kt += 32) {
    __syncthreads();                         // st writes done / prev Bs reads done
    {
      int col = t >> 2, kq = t & 3;          // 256 cols x 32 k
      g2lds16(BtO + (size_t)col * 256 + kt + kq * 8, (char*)Bs + t * 16);
    }
    __syncthreads();
    bf16x8 af = *(const bf16x8*)&st[(wm * 16 + lr) * 264 + kt + quad * 8];
    #pragma unroll
    for (int ni = 0; ni < 4; ++ni) {
      bf16x8 bf = *(const bf16x8*)&Bs[(wn * 64 + ni * 16 + lr) * 32 + quad * 8];
      acc[ni] = __builtin_amdgcn_mfma_f32_16x16x32_bf16(af, bf, acc[ni], 0, 0, 0);
    }
  }

  // fp32 NCHW stores: one wave's 4 quads cover each full 64-B line
  const int n4 = pix0 >> 12, hw0 = pix0 & 4095;
  #pragma unroll
  for (int ni = 0; ni < 4; ++ni) {
    int col = wn * 64 + ni * 16 + lr;
    float bv = out_b[col];
    float4 v;
    v.x = acc[ni][0] + bv; v.y = acc[ni][1] + bv;
    v.z = acc[ni][2] + bv; v.w = acc[ni][3] + bv;
    *(float4*)&out[(size_t)(n4 * 256 + col) * 4096 + hw0 + wm * 16 + quad * 4] = v;
  }
}

extern "C" void kernel_launch(void* const* d_in, const int* in_sizes, int n_in,
                              void* d_out, int out_size, void* d_ws, size_t ws_size,
                              hipStream_t stream) {
  const float* x      = (const float*)d_in[0];
  const float* dw_w   = (const float*)d_in[1];
  const float* dw_b   = (const float*)d_in[2];
  const float* ln_g   = (const float*)d_in[3];
  const float* ln_b   = (const float*)d_in[4];
  const float* off_w  = (const float*)d_in[5];
  const float* off_b  = (const float*)d_in[6];
  const float* mask_w = (const float*)d_in[7];
  const float* mask_b = (const float*)d_in[8];
  const float* inp_w  = (const float*)d_in[9];
  const float* inp_b  = (const float*)d_in[10];
  const float* out_w  = (const float*)d_in[11];
  const float* out_b  = (const float*)d_in[12];
  float* out = (float*)d_out;

  char* w0 = (char*)d_ws;
  __hip_bfloat16* xpu  = (__hip_bfloat16*)(w0);               //  8,388,608 B
  __hip_bfloat16* xT   = (__hip_bfloat16*)(w0 + 8388608);     //  8,388,608 B
  __hip_bfloat16* om   = (__hip_bfloat16*)(w0 + 16777216);    // 14,680,064 B
  __hip_bfloat16* BtI  = (__hip_bfloat16*)(w0 + 31457280);    //    131,072 B
  __hip_bfloat16* BtOM = (__hip_bfloat16*)(w0 + 31588352);    //    262,144 B
  __hip_bfloat16* BtO  = (__hip_bfloat16*)(w0 + 31850496);    //    131,072 B
  float*          bOM  = (float*)(w0 + 31981568);             //      2,048 B
  if (ws_size < 31983616) return;

  prep_xt_k<<<3072, 256, 0, stream>>>(x, inp_w, off_w, off_b, mask_w, mask_b,
                                      out_w, BtI, BtOM, BtO, bOM, xT);
  stage2_gi_k<<<512, 1024, 0, stream>>>(x, xT, dw_w, dw_b, ln_g, ln_b, BtOM, bOM,
                                        om, BtI, inp_b, xpu);
  fused_so_k<<<256, 1024, 0, stream>>>(xpu, om, BtO, out_b, out);
}

// Round 5
// 156.832 us; speedup vs baseline: 1.2148x; 1.0048x over previous
//
#include <hip/hip_runtime.h>
#include <hip/hip_bf16.h>
#include <math.h>

// R12b: identical to R12 (bench infra failed; resubmission).
// xT intermediate eliminated. gemm_i does its own NCHW->[px][ch] bf16
// transpose in LDS (one 64-px strip per block, A staged once, full-N output).
// prep is weights-only. fused_so split 512x512 for 2-4 blocks/CU TLP.
// 3 dispatches.

using bf16x8 = __attribute__((ext_vector_type(8))) short;
using f32x4  = __attribute__((ext_vector_type(4))) float;

#define GLOBAL_AS __attribute__((address_space(1)))
#define LDS_AS    __attribute__((address_space(3)))

static __device__ inline void g2lds16(const void* g, void* l) {
  __builtin_amdgcn_global_load_lds((const GLOBAL_AS int*)g, (LDS_AS int*)l, 16, 0, 0);
}
static __device__ inline unsigned short f2bf(float v) {
  __hip_bfloat16 b = __float2bfloat16(v);
  return *reinterpret_cast<unsigned short*>(&b);
}
static __device__ inline float us2f(unsigned short u) {
  union { unsigned u; float f; } c; c.u = ((unsigned)u) << 16; return c.f;
}

// ---------------- prep: weight transposes -> bf16 (weights only) ------------
__global__ __launch_bounds__(256) void prep_w_k(
    const float* __restrict__ inp_w, const float* __restrict__ off_w,
    const float* __restrict__ off_b, const float* __restrict__ mask_w,
    const float* __restrict__ mask_b, const float* __restrict__ out_w,
    __hip_bfloat16* __restrict__ BtI, __hip_bfloat16* __restrict__ BtOM,
    __hip_bfloat16* __restrict__ BtO, float* __restrict__ bOM)
{
  const int b = blockIdx.x, t = threadIdx.x;
  if (b < 256) {
    int n = b;
    BtI[n * 256 + t] = __float2bfloat16(inp_w[t * 256 + n]);
  } else if (b < 768) {
    int n = b - 256;
    float v = 0.f;
    if (n < 288) v = off_w[t * 288 + n];
    else if (n < 432) v = mask_w[t * 144 + (n - 288)];
    BtOM[n * 256 + t] = __float2bfloat16(v);
    if (b == 256) {
      for (int idx = t; idx < 512; idx += 256) {
        float bv = (idx < 288) ? off_b[idx] : ((idx < 432) ? mask_b[idx - 288] : 0.f);
        bOM[idx] = bv;
      }
    }
  } else {
    int n = b - 768;
    BtO[n * 256 + t] = __float2bfloat16(out_w[t * 256 + n]);
  }
}

// ---------------- K2: stage2 (dwconv+LN+GELU+OM GEMM) ∥ input-proj GEMM -----
// blocks 0..255  : stage2 row (64 px), conv direct from x via shfl
// blocks 256..511: gemm_i strip (64 px x 256 out), in-kernel NCHW transpose
__global__ __launch_bounds__(1024) void stage2_gi_k(
    const float* __restrict__ x,
    const float* __restrict__ dw_w, const float* __restrict__ dw_b,
    const float* __restrict__ ln_g, const float* __restrict__ ln_b,
    const __hip_bfloat16* __restrict__ BtOM, const float* __restrict__ bOM,
    __hip_bfloat16* __restrict__ om,
    const __hip_bfloat16* __restrict__ BtI, const float* __restrict__ inp_b,
    __hip_bfloat16* __restrict__ xpu)
{
  __shared__ __align__(16) char smem[62464];
  const int bid = blockIdx.x;
  const int t = threadIdx.x;

  if (bid >= 256) {
    // -------- input-proj GEMM strip: x(NCHW fp32) -> A bf16 -> xpu --------
    unsigned short* A = (unsigned short*)smem;            // [64][264] 33792 B
    float* ftile = (float*)(smem + 33792);                // [32][65] 8320 B
    short* Bs = (short*)(smem + 42112);                   // [256][32] 16384 B

    const int strip = bid - 256;                          // 0..255
    const int n4 = strip >> 6, hw0 = (strip & 63) * 64;
    const float* xb = x + (size_t)n4 * 1048576 + hw0;

    // transpose 8 chunks of 32 channels
    for (int ck = 0; ck < 8; ++ck) {
      const int ch0 = ck * 32;
      #pragma unroll
      for (int r = 0; r < 2; ++r) {
        int idx = t + r * 1024;                           // 2048 = 32ch * 64px
        int cl = idx >> 6, wl = idx & 63;
        ftile[cl * 65 + wl] = xb[(size_t)(ch0 + cl) * 4096 + wl];
      }
      __syncthreads();
      {
        int px = t >> 4, cq2 = t & 15;                    // 2 channels each
        unsigned short b0 = f2bf(ftile[(cq2 * 2) * 65 + px]);
        unsigned short b1 = f2bf(ftile[(cq2 * 2 + 1) * 65 + px]);
        *(unsigned*)&A[px * 264 + ch0 + cq2 * 2] =
            (unsigned)b0 | ((unsigned)b1 << 16);
      }
      __syncthreads();
    }

    // GEMM: M=64, N=256, K=256. 16 waves = 4m x 4n.
    const int wave = t >> 6, lane = t & 63;
    const int quad = lane >> 4, lr = lane & 15;
    const int wm = wave >> 2, wn = wave & 3;
    f32x4 acc[4];
    #pragma unroll
    for (int i = 0; i < 4; ++i) acc[i] = (f32x4){0.f, 0.f, 0.f, 0.f};

    for (int kt = 0; kt < 256; kt += 32) {
      __syncthreads();                       // prev Bs reads done
      {
        int col = t >> 2, kq = t & 3;        // 256 cols x 32 k
        g2lds16(BtI + (size_t)col * 256 + kt + kq * 8, (char*)Bs + t * 16);
      }
      __syncthreads();
      bf16x8 af = *(const bf16x8*)&A[(wm * 16 + lr) * 264 + kt + quad * 8];
      #pragma unroll
      for (int ni = 0; ni < 4; ++ni) {
        bf16x8 bf = *(const bf16x8*)&Bs[(wn * 64 + ni * 16 + lr) * 32 + quad * 8];
        acc[ni] = __builtin_amdgcn_mfma_f32_16x16x32_bf16(af, bf, acc[ni], 0, 0, 0);
      }
    }

    const size_t m0 = (size_t)strip * 64;
    #pragma unroll
    for (int ni = 0; ni < 4; ++ni) {
      int col = wn * 64 + ni * 16 + lr;
      float bv = inp_b[col];
      #pragma unroll
      for (int reg = 0; reg < 4; ++reg) {
        size_t m = m0 + wm * 16 + quad * 4 + reg;
        xpu[m * 256 + col] = __float2bfloat16(acc[ni][reg] + bv);
      }
    }
    return;
  }

  // -------- stage2 role --------
  unsigned short* x1t = (unsigned short*)smem;            // [64][264] 33792 B (persists into GEMM)
  float* psq  = (float*)(smem + 33792);                   // ps[1024]|pq[1024] 8192 B
  float* murs = (float*)(smem + 41984);                   // mu[64]|rs[64] 512 B
  short* Bs   = (short*)(smem + 33792);                   // GEMM phase: [448][32] 28672 B

  const int blk = ((bid & 7) << 5) | (bid >> 3);          // bijective XCD swizzle
  const int n4 = blk >> 6, h = blk & 63;
  const int w = t & 63, q = t >> 6;                       // lane = pixel w; wave = ch-group q

  // ---- depthwise 3x3 conv, direct from x (fp32 NCHW), halo via shfl ----
  const float* xb = x + (size_t)n4 * 1048576;             // [256][64][64]
  const bool hm = (h > 0), hp = (h < 63);
  float av[16];
  float s1 = 0.f, s2 = 0.f;

  #pragma unroll 2
  for (int j = 0; j < 8; ++j) {
    #pragma unroll
    for (int u = 0; u < 2; ++u) {
      const int c = q * 16 + 2 * j + u;
      const float* xc = xb + (size_t)c * 4096 + h * 64 + w;
      float v0 = hm ? xc[-64] : 0.f;
      float v1 = xc[0];
      float v2 = hp ? xc[64] : 0.f;
      const float* wp = dw_w + c * 9;                     // wave-uniform
      float a = dw_b[c];
      #pragma unroll
      for (int dh = 0; dh < 3; ++dh) {
        float v = (dh == 0) ? v0 : (dh == 1) ? v1 : v2;
        float vm = __shfl(v, w - 1, 64);
        float vp = __shfl(v, w + 1, 64);
        if (w == 0)  vm = 0.f;
        if (w == 63) vp = 0.f;
        a = fmaf(vm, wp[dh * 3 + 0], a);
        a = fmaf(v,  wp[dh * 3 + 1], a);
        a = fmaf(vp, wp[dh * 3 + 2], a);
      }
      s1 += a;
      s2 = fmaf(a, a, s2);
      av[2 * j + u] = a;
    }
  }

  psq[q * 64 + w] = s1;
  psq[1024 + q * 64 + w] = s2;
  __syncthreads();
  if (t < 64) {
    float a = 0.f, b = 0.f;
    #pragma unroll
    for (int j = 0; j < 16; ++j) { a += psq[j * 64 + t]; b += psq[1024 + j * 64 + t]; }
    float mu = a * (1.f / 256.f);
    murs[t] = mu;
    murs[64 + t] = rsqrtf(b * (1.f / 256.f) - mu * mu + 1e-5f);
  }
  __syncthreads();
  {                                          // LN + GELU on fp32 regs -> x1t bf16
    float mu = murs[w], rs = murs[64 + w];
    #pragma unroll
    for (int j = 0; j < 8; ++j) {
      int c = q * 16 + 2 * j;
      float y0 = fmaf((av[2 * j] - mu) * rs, ln_g[c], ln_b[c]);
      float y1 = fmaf((av[2 * j + 1] - mu) * rs, ln_g[c + 1], ln_b[c + 1]);
      float g0 = 0.5f * y0 * (1.f + erff(y0 * 0.70710678f));
      float g1 = 0.5f * y1 * (1.f + erff(y1 * 0.70710678f));
      *(unsigned*)&x1t[w * 264 + c] = (unsigned)f2bf(g0) | ((unsigned)f2bf(g1) << 16);
    }
  }
  __syncthreads();                           // x1t done; psq/murs dead (Bs aliases)

  // ---- OM GEMM: M=64, N=448 (432 valid), K=256. 16 waves = 4m x 4n. ----
  const int wave = t >> 6, lane = t & 63;
  const int quad = lane >> 4, lr = lane & 15;
  const int wm = wave >> 2, wn = wave & 3;
  f32x4 acc[7];
  #pragma unroll
  for (int i = 0; i < 7; ++i) acc[i] = (f32x4){0.f, 0.f, 0.f, 0.f};

  for (int kt = 0; kt < 256; kt += 32) {
    __syncthreads();                         // Bs reads from prev iter done
    {
      int col = t >> 2, kq = t & 3;
      g2lds16(BtOM + (size_t)col * 256 + kt + kq * 8, (char*)Bs + t * 16);
      int jj = t + 1024;
      if (jj < 1792) {
        col = jj >> 2; kq = jj & 3;
        g2lds16(BtOM + (size_t)col * 256 + kt + kq * 8, (char*)Bs + jj * 16);
      }
    }
    __syncthreads();
    bf16x8 af = *(const bf16x8*)&x1t[(wm * 16 + lr) * 264 + kt + quad * 8];
    #pragma unroll
    for (int ni = 0; ni < 7; ++ni) {
      bf16x8 bf = *(const bf16x8*)&Bs[(wn * 112 + ni * 16 + lr) * 32 + quad * 8];
      acc[ni] = __builtin_amdgcn_mfma_f32_16x16x32_bf16(af, bf, acc[ni], 0, 0, 0);
    }
  }

  const size_t pix0 = (size_t)n4 * 4096 + (size_t)h * 64;
  #pragma unroll
  for (int ni = 0; ni < 7; ++ni) {
    int col = wn * 112 + ni * 16 + lr;
    if (col < 432) {
      float bv = bOM[col];
      #pragma unroll
      for (int reg = 0; reg < 4; ++reg) {
        int m = wm * 16 + quad * 4 + reg;
        om[(pix0 + m) * 448 + col] = __float2bfloat16(acc[ni][reg] + bv);
      }
    }
  }
}

// ---------------- K3: sampling -> LDS tile -> output-proj GEMM -> fp32 NCHW -
// 512 blocks x 512 thr (32 px each). LDS 33 KB -> 3-4 blocks/CU.
__global__ __launch_bounds__(512) void fused_so_k(
    const __hip_bfloat16* __restrict__ xpu, const __hip_bfloat16* __restrict__ om,
    const __hip_bfloat16* __restrict__ BtO, const float* __restrict__ out_b,
    float* __restrict__ out)
{
  __shared__ __align__(16) char smem[33792];
  unsigned short* st = (unsigned short*)smem;          // samp tile [32][264] 16896 B
  short* Bs = (short*)(smem + 16896);                  // B-stage [256][32] 16384 B

  const int bid = blockIdx.x;                          // 512
  const int swz = ((bid & 7) << 6) | (bid >> 3);       // bijective XCD swizzle
  const int pix0 = swz << 5;                           // 32 consecutive pixels
  const int t = threadIdx.x;

  // ---- sampling: thread = (pixel pl 0..31, group g 0..15) ----
  {
    const int pl = t >> 4, g = t & 15;
    const int pix = pix0 + pl;
    const int n4s = pix >> 12;
    const int hw = pix & 4095;
    const int h = hw >> 6, w = hw & 63;
    const unsigned short* omp = (const unsigned short*)om + (size_t)pix * 448;

    float mk[9];
    {
      float mx = -1e30f;
      #pragma unroll
      for (int p = 0; p < 9; ++p) { mk[p] = us2f(omp[288 + g * 9 + p]); mx = fmaxf(mx, mk[p]); }
      float se = 0.f;
      #pragma unroll
      for (int p = 0; p < 9; ++p) { mk[p] = __expf(mk[p] - mx); se += mk[p]; }
      float inv = 1.f / se;
      #pragma unroll
      for (int p = 0; p < 9; ++p) mk[p] *= inv;
    }

    const __hip_bfloat16* xpg = xpu + (g << 4);
    float ax[16];
    #pragma unroll
    for (int i = 0; i < 16; ++i) ax[i] = 0.f;

    auto corner = [&](int iy, int ix, float wt) {
      if ((unsigned)(iy - 1) >= 64u || (unsigned)(ix - 1) >= 64u) return;
      const __hip_bfloat16* src =
          xpg + ((size_t)((n4s << 12) + (iy - 1) * 64 + (ix - 1)) << 8);
      uint4 u0 = *(const uint4*)src;
      uint4 u1 = *(const uint4*)(src + 8);
      const unsigned uu[8] = {u0.x, u0.y, u0.z, u0.w, u1.x, u1.y, u1.z, u1.w};
      #pragma unroll
      for (int i = 0; i < 8; ++i) {
        float lo = us2f((unsigned short)(uu[i] & 0xffff));
        float hi = us2f((unsigned short)(uu[i] >> 16));
        ax[2 * i + 0] = fmaf(wt, lo, ax[2 * i + 0]);
        ax[2 * i + 1] = fmaf(wt, hi, ax[2 * i + 1]);
      }
    };

    #pragma unroll
    for (int p = 0; p < 9; ++p) {
      float ox = us2f(omp[g * 18 + 2 * p]), oy = us2f(omp[g * 18 + 2 * p + 1]);
      float px = (float)(w + p / 3) + ox;
      float py = (float)(h + p % 3) + oy;
      float xf = floorf(px), yf = floorf(py);
      float wx = px - xf, wy = py - yf;
      int ix = (int)xf, iy = (int)yf;
      float m = mk[p];
      corner(iy,     ix,     (1.f - wy) * (1.f - wx) * m);
      corner(iy,     ix + 1, (1.f - wy) * wx * m);
      corner(iy + 1, ix,     wy * (1.f - wx) * m);
      corner(iy + 1, ix + 1, wy * wx * m);
    }

    unsigned short ub[16];
    #pragma unroll
    for (int i = 0; i < 16; ++i) ub[i] = f2bf(ax[i]);
    uint4 u0, u1;
    u0.x = (unsigned)ub[0] | ((unsigned)ub[1] << 16);
    u0.y = (unsigned)ub[2] | ((unsigned)ub[3] << 16);
    u0.z = (unsigned)ub[4] | ((unsigned)ub[5] << 16);
    u0.w = (unsigned)ub[6] | ((unsigned)ub[7] << 16);
    u1.x = (unsigned)ub[8] | ((unsigned)ub[9] << 16);
    u1.y = (unsigned)ub[10] | ((unsigned)ub[11] << 16);
    u1.z = (unsigned)ub[12] | ((unsigned)ub[13] << 16);
    u1.w = (unsigned)ub[14] | ((unsigned)ub[15] << 16);
    *(uint4*)&st[pl * 264 + g * 16] = u0;
    *(uint4*)&st[pl * 264 + g * 16 + 8] = u1;
  }

  // ---- out-proj GEMM: st(32x256) @ BtO^T. 8 waves = 2m x 4n. ----
  const int wave = t >> 6, lane = t & 63;
  const int quad = lane >> 4, lr = lane & 15;
  const int wm = wave >> 2, wn = wave & 3;
  f32x4 acc[4];
  #pragma unroll
  for (int i = 0; i < 4; ++i) acc[i] = (f32x4){0.f, 0.f, 0.f, 0.f};

  for (int kt = 0; kt < 256; kt += 32) {
    __syncthreads();                         // st writes done / prev Bs reads done
    {
      #pragma unroll
      for (int r = 0; r < 2; ++r) {
        int j = t + r * 512;                 // 1024 = 256 cols x 4 kq
        int col = j >> 2, kq = j & 3;
        g2lds16(BtO + (size_t)col * 256 + kt + kq * 8, (char*)Bs + j * 16);
      }
    }
    __syncthreads();
    bf16x8 af = *(const bf16x8*)&st[(wm * 16 + lr) * 264 + kt + quad * 8];
    #pragma unroll
    for (int ni = 0; ni < 4; ++ni) {
      bf16x8 bf = *(const bf16x8*)&Bs[(wn * 64 + ni * 16 + lr) * 32 + quad * 8];
      acc[ni] = __builtin_amdgcn_mfma_f32_16x16x32_bf16(af, bf, acc[ni], 0, 0, 0);
    }
  }

  // fp32 NCHW stores: one wave's 4 quads cover each full 64-B line
  const int n4 = pix0 >> 12, hw0 = pix0 & 4095;
  #pragma unroll
  for (int ni = 0; ni < 4; ++ni) {
    int col = wn * 64 + ni * 16 + lr;
    float bv = out_b[col];
    float4 v;
    v.x = acc[ni][0] + bv; v.y = acc[ni][1] + bv;
    v.z = acc[ni][2] + bv; v.w = acc[ni][3] + bv;
    *(float4*)&out[(size_t)(n4 * 256 + col) * 4096 + hw0 + wm * 16 + quad * 4] = v;
  }
}

extern "C" void kernel_launch(void* const* d_in, const int* in_sizes, int n_in,
                              void* d_out, int out_size, void* d_ws, size_t ws_size,
                              hipStream_t stream) {
  const float* x      = (const float*)d_in[0];
  const float* dw_w   = (const float*)d_in[1];
  const float* dw_b   = (const float*)d_in[2];
  const float* ln_g   = (const float*)d_in[3];
  const float* ln_b   = (const float*)d_in[4];
  const float* off_w  = (const float*)d_in[5];
  const float* off_b  = (const float*)d_in[6];
  const float* mask_w = (const float*)d_in[7];
  const float* mask_b = (const float*)d_in[8];
  const float* inp_w  = (const float*)d_in[9];
  const float* inp_b  = (const float*)d_in[10];
  const float* out_w  = (const float*)d_in[11];
  const float* out_b  = (const float*)d_in[12];
  float* out = (float*)d_out;

  char* w0 = (char*)d_ws;
  __hip_bfloat16* xpu  = (__hip_bfloat16*)(w0);               //  8,388,608 B
  __hip_bfloat16* om   = (__hip_bfloat16*)(w0 + 8388608);     // 14,680,064 B
  __hip_bfloat16* BtI  = (__hip_bfloat16*)(w0 + 23068672);    //    131,072 B
  __hip_bfloat16* BtOM = (__hip_bfloat16*)(w0 + 23199744);    //    262,144 B
  __hip_bfloat16* BtO  = (__hip_bfloat16*)(w0 + 23461888);    //    131,072 B
  float*          bOM  = (float*)(w0 + 23592960);             //      2,048 B
  if (ws_size < 23595008) return;

  prep_w_k<<<1024, 256, 0, stream>>>(inp_w, off_w, off_b, mask_w, mask_b,
                                     out_w, BtI, BtOM, BtO, bOM);
  stage2_gi_k<<<512, 1024, 0, stream>>>(x, dw_w, dw_b, ln_g, ln_b, BtOM, bOM,
                                        om, BtI, inp_b, xpu);
  fused_so_k<<<512, 512, 0, stream>>>(xpu, om, BtO, out_b, out);
}

// Round 6
// 152.162 us; speedup vs baseline: 1.2521x; 1.0307x over previous
//
#include <hip/hip_runtime.h>
#include <hip/hip_bf16.h>
#include <math.h>

// R13: 2-phase pipelined B-staging (T3 minimum recipe) in all three GEMM
// phases: double-buffered B tile, STAGE(k+1) issued BEFORE compute(k), one
// barrier per step. A-fragments held in registers (8 x bf16x8/wave) so the
// A LDS tile can be re-used as the second B buffer. fused_so pre-issues its
// step-0 stage at kernel entry (hides under sampling). gemm_i transpose
// prefetches next fp32 chunk into regs across the convert phase.

using bf16x8 = __attribute__((ext_vector_type(8))) short;
using f32x4  = __attribute__((ext_vector_type(4))) float;

#define GLOBAL_AS __attribute__((address_space(1)))
#define LDS_AS    __attribute__((address_space(3)))

static __device__ inline void g2lds16(const void* g, void* l) {
  __builtin_amdgcn_global_load_lds((const GLOBAL_AS int*)g, (LDS_AS int*)l, 16, 0, 0);
}
static __device__ inline unsigned short f2bf(float v) {
  __hip_bfloat16 b = __float2bfloat16(v);
  return *reinterpret_cast<unsigned short*>(&b);
}
static __device__ inline float us2f(unsigned short u) {
  union { unsigned u; float f; } c; c.u = ((unsigned)u) << 16; return c.f;
}

// ---------------- prep: weight transposes -> bf16 (weights only) ------------
__global__ __launch_bounds__(256) void prep_w_k(
    const float* __restrict__ inp_w, const float* __restrict__ off_w,
    const float* __restrict__ off_b, const float* __restrict__ mask_w,
    const float* __restrict__ mask_b, const float* __restrict__ out_w,
    __hip_bfloat16* __restrict__ BtI, __hip_bfloat16* __restrict__ BtOM,
    __hip_bfloat16* __restrict__ BtO, float* __restrict__ bOM)
{
  const int b = blockIdx.x, t = threadIdx.x;
  if (b < 256) {
    int n = b;
    BtI[n * 256 + t] = __float2bfloat16(inp_w[t * 256 + n]);
  } else if (b < 768) {
    int n = b - 256;
    float v = 0.f;
    if (n < 288) v = off_w[t * 288 + n];
    else if (n < 432) v = mask_w[t * 144 + (n - 288)];
    BtOM[n * 256 + t] = __float2bfloat16(v);
    if (b == 256) {
      for (int idx = t; idx < 512; idx += 256) {
        float bv = (idx < 288) ? off_b[idx] : ((idx < 432) ? mask_b[idx - 288] : 0.f);
        bOM[idx] = bv;
      }
    }
  } else {
    int n = b - 768;
    BtO[n * 256 + t] = __float2bfloat16(out_w[t * 256 + n]);
  }
}

// ---------------- K2: stage2 (dwconv+LN+GELU+OM GEMM) ∥ input-proj GEMM -----
// blocks 0..255  : stage2 row (64 px); conv via shfl; OM GEMM 2-phase dbuf
// blocks 256..511: gemm_i strip (64 px x 256); transpose + 2-phase dbuf GEMM
__global__ __launch_bounds__(1024) void stage2_gi_k(
    const float* __restrict__ x,
    const float* __restrict__ dw_w, const float* __restrict__ dw_b,
    const float* __restrict__ ln_g, const float* __restrict__ ln_b,
    const __hip_bfloat16* __restrict__ BtOM, const float* __restrict__ bOM,
    __hip_bfloat16* __restrict__ om,
    const __hip_bfloat16* __restrict__ BtI, const float* __restrict__ inp_b,
    __hip_bfloat16* __restrict__ xpu)
{
  __shared__ __align__(16) char smem[57344];
  const int bid = blockIdx.x;
  const int t = threadIdx.x;

  if (bid >= 256) {
    // -------- input-proj GEMM strip: x(NCHW fp32) -> A bf16 -> xpu --------
    unsigned short* A = (unsigned short*)smem;            // [64][264] 33792 B
    float* ftile = (float*)(smem + 33792);                // [32][65] 8320 B

    const int strip = bid - 256;                          // 0..255
    const int n4 = strip >> 6, hw0 = (strip & 63) * 64;
    const float* xb = x + (size_t)n4 * 1048576 + hw0;

    const int cl0 = t >> 6, wl0 = t & 63;                 // load slots
    const int cl1 = (t + 1024) >> 6, wl1 = (t + 1024) & 63;
    float p0 = xb[(size_t)cl0 * 4096 + wl0];
    float p1 = xb[(size_t)cl1 * 4096 + wl1];

    for (int ck = 0; ck < 8; ++ck) {
      const int ch0 = ck * 32;
      ftile[cl0 * 65 + wl0] = p0;
      ftile[cl1 * 65 + wl1] = p1;
      if (ck < 7) {                                       // prefetch next chunk
        p0 = xb[(size_t)(ch0 + 32 + cl0) * 4096 + wl0];
        p1 = xb[(size_t)(ch0 + 32 + cl1) * 4096 + wl1];
      }
      __syncthreads();
      {
        int px = t >> 4, cq2 = t & 15;                    // 2 channels each
        unsigned short b0 = f2bf(ftile[(cq2 * 2) * 65 + px]);
        unsigned short b1 = f2bf(ftile[(cq2 * 2 + 1) * 65 + px]);
        *(unsigned*)&A[px * 264 + ch0 + cq2 * 2] =
            (unsigned)b0 | ((unsigned)b1 << 16);
      }
      __syncthreads();
    }

    // GEMM: M=64, N=256, K=256. 16 waves = 4m x 4n. 2-phase dbuf.
    const int wave = t >> 6, lane = t & 63;
    const int quad = lane >> 4, lr = lane & 15;
    const int wm = wave >> 2, wn = wave & 3;

    bf16x8 areg[8];
    #pragma unroll
    for (int s = 0; s < 8; ++s)
      areg[s] = *(const bf16x8*)&A[(wm * 16 + lr) * 264 + s * 32 + quad * 8];
    __syncthreads();                         // all A reads done; A region free

    auto stageI = [&](int s, int buf) {      // [256][32] = 1024 x 16B
      int col = t >> 2, kq = t & 3;
      g2lds16(BtI + (size_t)col * 256 + s * 32 + kq * 8,
              smem + buf * 16384 + t * 16);
    };

    f32x4 acc[4];
    #pragma unroll
    for (int i = 0; i < 4; ++i) acc[i] = (f32x4){0.f, 0.f, 0.f, 0.f};

    stageI(0, 0);
    __syncthreads();
    #pragma unroll
    for (int s = 0; s < 8; ++s) {
      if (s < 7) stageI(s + 1, (s + 1) & 1);
      const short* B = (const short*)(smem + (s & 1) * 16384);
      bf16x8 bfr[4];
      #pragma unroll
      for (int ni = 0; ni < 4; ++ni)
        bfr[ni] = *(const bf16x8*)&B[(wn * 64 + ni * 16 + lr) * 32 + quad * 8];
      #pragma unroll
      for (int ni = 0; ni < 4; ++ni)
        acc[ni] = __builtin_amdgcn_mfma_f32_16x16x32_bf16(areg[s], bfr[ni], acc[ni], 0, 0, 0);
      __syncthreads();
    }

    const size_t m0 = (size_t)strip * 64;
    #pragma unroll
    for (int ni = 0; ni < 4; ++ni) {
      int col = wn * 64 + ni * 16 + lr;
      float bv = inp_b[col];
      #pragma unroll
      for (int reg = 0; reg < 4; ++reg) {
        size_t m = m0 + wm * 16 + quad * 4 + reg;
        xpu[m * 256 + col] = __float2bfloat16(acc[ni][reg] + bv);
      }
    }
    return;
  }

  // -------- stage2 role --------
  unsigned short* x1t = (unsigned short*)smem;            // [64][264] 33792 B
  float* psq  = (float*)(smem + 33792);                   // ps[1024]|pq[1024] 8192 B
  float* murs = (float*)(smem + 41984);                   // mu[64]|rs[64] 512 B

  const int blk = ((bid & 7) << 5) | (bid >> 3);          // bijective XCD swizzle
  const int n4 = blk >> 6, h = blk & 63;
  const int w = t & 63, q = t >> 6;                       // lane = pixel w; wave = ch-group q

  // ---- depthwise 3x3 conv, direct from x (fp32 NCHW), halo via shfl ----
  const float* xb = x + (size_t)n4 * 1048576;             // [256][64][64]
  const bool hm = (h > 0), hp = (h < 63);
  float av[16];
  float s1 = 0.f, s2 = 0.f;

  #pragma unroll 2
  for (int j = 0; j < 8; ++j) {
    #pragma unroll
    for (int u = 0; u < 2; ++u) {
      const int c = q * 16 + 2 * j + u;
      const float* xc = xb + (size_t)c * 4096 + h * 64 + w;
      float v0 = hm ? xc[-64] : 0.f;
      float v1 = xc[0];
      float v2 = hp ? xc[64] : 0.f;
      const float* wp = dw_w + c * 9;                     // wave-uniform
      float a = dw_b[c];
      #pragma unroll
      for (int dh = 0; dh < 3; ++dh) {
        float v = (dh == 0) ? v0 : (dh == 1) ? v1 : v2;
        float vm = __shfl(v, w - 1, 64);
        float vp = __shfl(v, w + 1, 64);
        if (w == 0)  vm = 0.f;
        if (w == 63) vp = 0.f;
        a = fmaf(vm, wp[dh * 3 + 0], a);
        a = fmaf(v,  wp[dh * 3 + 1], a);
        a = fmaf(vp, wp[dh * 3 + 2], a);
      }
      s1 += a;
      s2 = fmaf(a, a, s2);
      av[2 * j + u] = a;
    }
  }

  psq[q * 64 + w] = s1;
  psq[1024 + q * 64 + w] = s2;
  __syncthreads();
  if (t < 64) {
    float a = 0.f, b = 0.f;
    #pragma unroll
    for (int j = 0; j < 16; ++j) { a += psq[j * 64 + t]; b += psq[1024 + j * 64 + t]; }
    float mu = a * (1.f / 256.f);
    murs[t] = mu;
    murs[64 + t] = rsqrtf(b * (1.f / 256.f) - mu * mu + 1e-5f);
  }
  __syncthreads();
  {                                          // LN + GELU on fp32 regs -> x1t bf16
    float mu = murs[w], rs = murs[64 + w];
    #pragma unroll
    for (int j = 0; j < 8; ++j) {
      int c = q * 16 + 2 * j;
      float y0 = fmaf((av[2 * j] - mu) * rs, ln_g[c], ln_b[c]);
      float y1 = fmaf((av[2 * j + 1] - mu) * rs, ln_g[c + 1], ln_b[c + 1]);
      float g0 = 0.5f * y0 * (1.f + erff(y0 * 0.70710678f));
      float g1 = 0.5f * y1 * (1.f + erff(y1 * 0.70710678f));
      *(unsigned*)&x1t[w * 264 + c] = (unsigned)f2bf(g0) | ((unsigned)f2bf(g1) << 16);
    }
  }
  __syncthreads();

  // ---- OM GEMM: M=64, N=448 (432 valid), K=256. 16 waves = 4m x 4n. ----
  const int wave = t >> 6, lane = t & 63;
  const int quad = lane >> 4, lr = lane & 15;
  const int wm = wave >> 2, wn = wave & 3;

  bf16x8 areg[8];
  #pragma unroll
  for (int s = 0; s < 8; ++s)
    areg[s] = *(const bf16x8*)&x1t[(wm * 16 + lr) * 264 + s * 32 + quad * 8];
  __syncthreads();                           // all A reads done; x1t free

  auto stageOM = [&](int s, int buf) {       // [448][32] = 1792 x 16B
    char* dst = smem + buf * 28672;
    int col = t >> 2, kq = t & 3;
    g2lds16(BtOM + (size_t)col * 256 + s * 32 + kq * 8, dst + t * 16);
    int jj = t + 1024;
    if (jj < 1792) {
      int col2 = jj >> 2, kq2 = jj & 3;
      g2lds16(BtOM + (size_t)col2 * 256 + s * 32 + kq2 * 8, dst + jj * 16);
    }
  };

  f32x4 acc[7];
  #pragma unroll
  for (int i = 0; i < 7; ++i) acc[i] = (f32x4){0.f, 0.f, 0.f, 0.f};

  stageOM(0, 0);
  __syncthreads();
  #pragma unroll
  for (int s = 0; s < 8; ++s) {
    if (s < 7) stageOM(s + 1, (s + 1) & 1);
    const short* B = (const short*)(smem + (s & 1) * 28672);
    bf16x8 bfr[7];
    #pragma unroll
    for (int ni = 0; ni < 7; ++ni)
      bfr[ni] = *(const bf16x8*)&B[(wn * 112 + ni * 16 + lr) * 32 + quad * 8];
    #pragma unroll
    for (int ni = 0; ni < 7; ++ni)
      acc[ni] = __builtin_amdgcn_mfma_f32_16x16x32_bf16(areg[s], bfr[ni], acc[ni], 0, 0, 0);
    __syncthreads();
  }

  const size_t pix0 = (size_t)n4 * 4096 + (size_t)h * 64;
  #pragma unroll
  for (int ni = 0; ni < 7; ++ni) {
    int col = wn * 112 + ni * 16 + lr;
    if (col < 432) {
      float bv = bOM[col];
      #pragma unroll
      for (int reg = 0; reg < 4; ++reg) {
        int m = wm * 16 + quad * 4 + reg;
        om[(pix0 + m) * 448 + col] = __float2bfloat16(acc[ni][reg] + bv);
      }
    }
  }
}

// ---------------- K3: sampling -> LDS tile -> output-proj GEMM -> fp32 NCHW -
// 512 blocks x 512 thr (32 px each). 2-phase dbuf B; step-0 staged at entry.
__global__ __launch_bounds__(512) void fused_so_k(
    const __hip_bfloat16* __restrict__ xpu, const __hip_bfloat16* __restrict__ om,
    const __hip_bfloat16* __restrict__ BtO, const float* __restrict__ out_b,
    float* __restrict__ out)
{
  __shared__ __align__(16) char smem[49664];
  unsigned short* st = (unsigned short*)smem;          // samp tile [32][264] 16896 B
  // Bs dbuf: smem+16896 (+16384 each)

  const int bid = blockIdx.x;                          // 512
  const int swz = ((bid & 7) << 6) | (bid >> 3);       // bijective XCD swizzle
  const int pix0 = swz << 5;                           // 32 consecutive pixels
  const int t = threadIdx.x;

  auto stageO = [&](int s, int buf) {                  // [256][32] = 1024 x 16B
    char* dst = smem + 16896 + buf * 16384;
    #pragma unroll
    for (int r = 0; r < 2; ++r) {
      int j = t + r * 512;
      int col = j >> 2, kq = j & 3;
      g2lds16(BtO + (size_t)col * 256 + s * 32 + kq * 8, dst + j * 16);
    }
  };

  stageO(0, 0);                                        // hides under sampling

  // ---- sampling: thread = (pixel pl 0..31, group g 0..15) ----
  {
    const int pl = t >> 4, g = t & 15;
    const int pix = pix0 + pl;
    const int n4s = pix >> 12;
    const int hw = pix & 4095;
    const int h = hw >> 6, w = hw & 63;
    const unsigned short* omp = (const unsigned short*)om + (size_t)pix * 448;

    float mk[9];
    {
      float mx = -1e30f;
      #pragma unroll
      for (int p = 0; p < 9; ++p) { mk[p] = us2f(omp[288 + g * 9 + p]); mx = fmaxf(mx, mk[p]); }
      float se = 0.f;
      #pragma unroll
      for (int p = 0; p < 9; ++p) { mk[p] = __expf(mk[p] - mx); se += mk[p]; }
      float inv = 1.f / se;
      #pragma unroll
      for (int p = 0; p < 9; ++p) mk[p] *= inv;
    }

    const __hip_bfloat16* xpg = xpu + (g << 4);
    float ax[16];
    #pragma unroll
    for (int i = 0; i < 16; ++i) ax[i] = 0.f;

    auto corner = [&](int iy, int ix, float wt) {
      if ((unsigned)(iy - 1) >= 64u || (unsigned)(ix - 1) >= 64u) return;
      const __hip_bfloat16* src =
          xpg + ((size_t)((n4s << 12) + (iy - 1) * 64 + (ix - 1)) << 8);
      uint4 u0 = *(const uint4*)src;
      uint4 u1 = *(const uint4*)(src + 8);
      const unsigned uu[8] = {u0.x, u0.y, u0.z, u0.w, u1.x, u1.y, u1.z, u1.w};
      #pragma unroll
      for (int i = 0; i < 8; ++i) {
        float lo = us2f((unsigned short)(uu[i] & 0xffff));
        float hi = us2f((unsigned short)(uu[i] >> 16));
        ax[2 * i + 0] = fmaf(wt, lo, ax[2 * i + 0]);
        ax[2 * i + 1] = fmaf(wt, hi, ax[2 * i + 1]);
      }
    };

    #pragma unroll
    for (int p = 0; p < 9; ++p) {
      float ox = us2f(omp[g * 18 + 2 * p]), oy = us2f(omp[g * 18 + 2 * p + 1]);
      float px = (float)(w + p / 3) + ox;
      float py = (float)(h + p % 3) + oy;
      float xf = floorf(px), yf = floorf(py);
      float wx = px - xf, wy = py - yf;
      int ix = (int)xf, iy = (int)yf;
      float m = mk[p];
      corner(iy,     ix,     (1.f - wy) * (1.f - wx) * m);
      corner(iy,     ix + 1, (1.f - wy) * wx * m);
      corner(iy + 1, ix,     wy * (1.f - wx) * m);
      corner(iy + 1, ix + 1, wy * wx * m);
    }

    unsigned short ub[16];
    #pragma unroll
    for (int i = 0; i < 16; ++i) ub[i] = f2bf(ax[i]);
    uint4 u0, u1;
    u0.x = (unsigned)ub[0] | ((unsigned)ub[1] << 16);
    u0.y = (unsigned)ub[2] | ((unsigned)ub[3] << 16);
    u0.z = (unsigned)ub[4] | ((unsigned)ub[5] << 16);
    u0.w = (unsigned)ub[6] | ((unsigned)ub[7] << 16);
    u1.x = (unsigned)ub[8] | ((unsigned)ub[9] << 16);
    u1.y = (unsigned)ub[10] | ((unsigned)ub[11] << 16);
    u1.z = (unsigned)ub[12] | ((unsigned)ub[13] << 16);
    u1.w = (unsigned)ub[14] | ((unsigned)ub[15] << 16);
    *(uint4*)&st[pl * 264 + g * 16] = u0;
    *(uint4*)&st[pl * 264 + g * 16 + 8] = u1;
  }
  __syncthreads();                           // st ready; stage0 drained

  // ---- out-proj GEMM: st(32x256) @ BtO^T. 8 waves = 2m x 4n. 2-phase. ----
  const int wave = t >> 6, lane = t & 63;
  const int quad = lane >> 4, lr = lane & 15;
  const int wm = wave >> 2, wn = wave & 3;

  bf16x8 areg[8];
  #pragma unroll
  for (int s = 0; s < 8; ++s)
    areg[s] = *(const bf16x8*)&st[(wm * 16 + lr) * 264 + s * 32 + quad * 8];

  f32x4 acc[4];
  #pragma unroll
  for (int i = 0; i < 4; ++i) acc[i] = (f32x4){0.f, 0.f, 0.f, 0.f};

  #pragma unroll
  for (int s = 0; s < 8; ++s) {
    if (s < 7) stageO(s + 1, (s + 1) & 1);
    const short* B = (const short*)(smem + 16896 + (s & 1) * 16384);
    bf16x8 bfr[4];
    #pragma unroll
    for (int ni = 0; ni < 4; ++ni)
      bfr[ni] = *(const bf16x8*)&B[(wn * 64 + ni * 16 + lr) * 32 + quad * 8];
    #pragma unroll
    for (int ni = 0; ni < 4; ++ni)
      acc[ni] = __builtin_amdgcn_mfma_f32_16x16x32_bf16(areg[s], bfr[ni], acc[ni], 0, 0, 0);
    __syncthreads();
  }

  // fp32 NCHW stores: one wave's 4 quads cover each full 64-B line
  const int n4 = pix0 >> 12, hw0 = pix0 & 4095;
  #pragma unroll
  for (int ni = 0; ni < 4; ++ni) {
    int col = wn * 64 + ni * 16 + lr;
    float bv = out_b[col];
    float4 v;
    v.x = acc[ni][0] + bv; v.y = acc[ni][1] + bv;
    v.z = acc[ni][2] + bv; v.w = acc[ni][3] + bv;
    *(float4*)&out[(size_t)(n4 * 256 + col) * 4096 + hw0 + wm * 16 + quad * 4] = v;
  }
}

extern "C" void kernel_launch(void* const* d_in, const int* in_sizes, int n_in,
                              void* d_out, int out_size, void* d_ws, size_t ws_size,
                              hipStream_t stream) {
  const float* x      = (const float*)d_in[0];
  const float* dw_w   = (const float*)d_in[1];
  const float* dw_b   = (const float*)d_in[2];
  const float* ln_g   = (const float*)d_in[3];
  const float* ln_b   = (const float*)d_in[4];
  const float* off_w  = (const float*)d_in[5];
  const float* off_b  = (const float*)d_in[6];
  const float* mask_w = (const float*)d_in[7];
  const float* mask_b = (const float*)d_in[8];
  const float* inp_w  = (const float*)d_in[9];
  const float* inp_b  = (const float*)d_in[10];
  const float* out_w  = (const float*)d_in[11];
  const float* out_b  = (const float*)d_in[12];
  float* out = (float*)d_out;

  char* w0 = (char*)d_ws;
  __hip_bfloat16* xpu  = (__hip_bfloat16*)(w0);               //  8,388,608 B
  __hip_bfloat16* om   = (__hip_bfloat16*)(w0 + 8388608);     // 14,680,064 B
  __hip_bfloat16* BtI  = (__hip_bfloat16*)(w0 + 23068672);    //    131,072 B
  __hip_bfloat16* BtOM = (__hip_bfloat16*)(w0 + 23199744);    //    262,144 B
  __hip_bfloat16* BtO  = (__hip_bfloat16*)(w0 + 23461888);    //    131,072 B
  float*          bOM  = (float*)(w0 + 23592960);             //      2,048 B
  if (ws_size < 23595008) return;

  prep_w_k<<<1024, 256, 0, stream>>>(inp_w, off_w, off_b, mask_w, mask_b,
                                     out_w, BtI, BtOM, BtO, bOM);
  stage2_gi_k<<<512, 1024, 0, stream>>>(x, dw_w, dw_b, ln_g, ln_b, BtOM, bOM,
                                        om, BtI, inp_b, xpu);
  fused_so_k<<<512, 512, 0, stream>>>(xpu, om, BtO, out_b, out);
}

// Round 7
// 146.962 us; speedup vs baseline: 1.2964x; 1.0354x over previous
//
#include <hip/hip_runtime.h>
#include <hip/hip_bf16.h>
#include <math.h>

// R14: om intermediate eliminated. K2 stage2-role = conv+LN+GELU -> x1 global
// (bf16, 8.4MB). K3 absorbs the offset/mask GEMM: x1 tile -> OM GEMM (dbuf)
// -> Som in LDS (never global) -> sampling -> out-proj GEMM. LDS phase-aliased
// (x1s->st, Bom0->Som, Bom1->BtO dbuf), peak 78.3KB = 2 blocks/CU.
// gemm_i role and conv kept from R13 (verified).

using bf16x8 = __attribute__((ext_vector_type(8))) short;
using f32x4  = __attribute__((ext_vector_type(4))) float;

#define GLOBAL_AS __attribute__((address_space(1)))
#define LDS_AS    __attribute__((address_space(3)))

static __device__ inline void g2lds16(const void* g, void* l) {
  __builtin_amdgcn_global_load_lds((const GLOBAL_AS int*)g, (LDS_AS int*)l, 16, 0, 0);
}
static __device__ inline unsigned short f2bf(float v) {
  __hip_bfloat16 b = __float2bfloat16(v);
  return *reinterpret_cast<unsigned short*>(&b);
}
static __device__ inline float us2f(unsigned short u) {
  union { unsigned u; float f; } c; c.u = ((unsigned)u) << 16; return c.f;
}

// ---------------- prep: weight transposes -> bf16 (weights only) ------------
__global__ __launch_bounds__(256) void prep_w_k(
    const float* __restrict__ inp_w, const float* __restrict__ off_w,
    const float* __restrict__ off_b, const float* __restrict__ mask_w,
    const float* __restrict__ mask_b, const float* __restrict__ out_w,
    __hip_bfloat16* __restrict__ BtI, __hip_bfloat16* __restrict__ BtOM,
    __hip_bfloat16* __restrict__ BtO, float* __restrict__ bOM)
{
  const int b = blockIdx.x, t = threadIdx.x;
  if (b < 256) {
    int n = b;
    BtI[n * 256 + t] = __float2bfloat16(inp_w[t * 256 + n]);
  } else if (b < 768) {
    int n = b - 256;
    float v = 0.f;
    if (n < 288) v = off_w[t * 288 + n];
    else if (n < 432) v = mask_w[t * 144 + (n - 288)];
    BtOM[n * 256 + t] = __float2bfloat16(v);
    if (b == 256) {
      for (int idx = t; idx < 512; idx += 256) {
        float bv = (idx < 288) ? off_b[idx] : ((idx < 432) ? mask_b[idx - 288] : 0.f);
        bOM[idx] = bv;
      }
    }
  } else {
    int n = b - 768;
    BtO[n * 256 + t] = __float2bfloat16(out_w[t * 256 + n]);
  }
}

// ---------------- K2: conv+LN+GELU -> x1 ∥ input-proj GEMM ------------------
// blocks 0..255  : stage2 row (64 px); conv via shfl; write x1 bf16 global
// blocks 256..511: gemm_i strip (R13 structure, 2-phase dbuf)
__global__ __launch_bounds__(1024) void stage2_gi_k(
    const float* __restrict__ x,
    const float* __restrict__ dw_w, const float* __restrict__ dw_b,
    const float* __restrict__ ln_g, const float* __restrict__ ln_b,
    const __hip_bfloat16* __restrict__ BtI, const float* __restrict__ inp_b,
    __hip_bfloat16* __restrict__ xpu, __hip_bfloat16* __restrict__ x1g)
{
  __shared__ __align__(16) char smem[42496];
  const int bid = blockIdx.x;
  const int t = threadIdx.x;

  if (bid >= 256) {
    // -------- input-proj GEMM strip: x(NCHW fp32) -> A bf16 -> xpu --------
    unsigned short* A = (unsigned short*)smem;            // [64][264] 33792 B
    float* ftile = (float*)(smem + 33792);                // [32][65] 8320 B

    const int strip = bid - 256;                          // 0..255
    const int n4 = strip >> 6, hw0 = (strip & 63) * 64;
    const float* xb = x + (size_t)n4 * 1048576 + hw0;

    const int cl0 = t >> 6, wl0 = t & 63;                 // load slots
    const int cl1 = (t + 1024) >> 6, wl1 = (t + 1024) & 63;
    float p0 = xb[(size_t)cl0 * 4096 + wl0];
    float p1 = xb[(size_t)cl1 * 4096 + wl1];

    for (int ck = 0; ck < 8; ++ck) {
      const int ch0 = ck * 32;
      ftile[cl0 * 65 + wl0] = p0;
      ftile[cl1 * 65 + wl1] = p1;
      if (ck < 7) {                                       // prefetch next chunk
        p0 = xb[(size_t)(ch0 + 32 + cl0) * 4096 + wl0];
        p1 = xb[(size_t)(ch0 + 32 + cl1) * 4096 + wl1];
      }
      __syncthreads();
      {
        int px = t >> 4, cq2 = t & 15;                    // 2 channels each
        unsigned short b0 = f2bf(ftile[(cq2 * 2) * 65 + px]);
        unsigned short b1 = f2bf(ftile[(cq2 * 2 + 1) * 65 + px]);
        *(unsigned*)&A[px * 264 + ch0 + cq2 * 2] =
            (unsigned)b0 | ((unsigned)b1 << 16);
      }
      __syncthreads();
    }

    // GEMM: M=64, N=256, K=256. 16 waves = 4m x 4n. 2-phase dbuf in A region.
    const int wave = t >> 6, lane = t & 63;
    const int quad = lane >> 4, lr = lane & 15;
    const int wm = wave >> 2, wn = wave & 3;

    bf16x8 areg[8];
    #pragma unroll
    for (int s = 0; s < 8; ++s)
      areg[s] = *(const bf16x8*)&A[(wm * 16 + lr) * 264 + s * 32 + quad * 8];
    __syncthreads();                         // all A reads done; A region free

    auto stageI = [&](int s, int buf) {      // [256][32] = 1024 x 16B
      int col = t >> 2, kq = t & 3;
      g2lds16(BtI + (size_t)col * 256 + s * 32 + kq * 8,
              smem + buf * 16384 + t * 16);
    };

    f32x4 acc[4];
    #pragma unroll
    for (int i = 0; i < 4; ++i) acc[i] = (f32x4){0.f, 0.f, 0.f, 0.f};

    stageI(0, 0);
    __syncthreads();
    #pragma unroll
    for (int s = 0; s < 8; ++s) {
      if (s < 7) stageI(s + 1, (s + 1) & 1);
      const short* B = (const short*)(smem + (s & 1) * 16384);
      bf16x8 bfr[4];
      #pragma unroll
      for (int ni = 0; ni < 4; ++ni)
        bfr[ni] = *(const bf16x8*)&B[(wn * 64 + ni * 16 + lr) * 32 + quad * 8];
      #pragma unroll
      for (int ni = 0; ni < 4; ++ni)
        acc[ni] = __builtin_amdgcn_mfma_f32_16x16x32_bf16(areg[s], bfr[ni], acc[ni], 0, 0, 0);
      __syncthreads();
    }

    const size_t m0 = (size_t)strip * 64;
    #pragma unroll
    for (int ni = 0; ni < 4; ++ni) {
      int col = wn * 64 + ni * 16 + lr;
      float bv = inp_b[col];
      #pragma unroll
      for (int reg = 0; reg < 4; ++reg) {
        size_t m = m0 + wm * 16 + quad * 4 + reg;
        xpu[m * 256 + col] = __float2bfloat16(acc[ni][reg] + bv);
      }
    }
    return;
  }

  // -------- stage2 role: conv + LN + GELU -> x1 global --------
  unsigned short* x1t = (unsigned short*)smem;            // [64][264] 33792 B
  float* psq  = (float*)(smem + 33792);                   // ps[1024]|pq[1024] 8192 B
  float* murs = (float*)(smem + 41984);                   // mu[64]|rs[64] 512 B

  const int blk = ((bid & 7) << 5) | (bid >> 3);          // bijective XCD swizzle
  const int n4 = blk >> 6, h = blk & 63;
  const int w = t & 63, q = t >> 6;                       // lane = pixel w; wave = ch-group q

  const float* xb = x + (size_t)n4 * 1048576;             // [256][64][64]
  const bool hm = (h > 0), hp = (h < 63);
  float av[16];
  float s1 = 0.f, s2 = 0.f;

  #pragma unroll 2
  for (int j = 0; j < 8; ++j) {
    #pragma unroll
    for (int u = 0; u < 2; ++u) {
      const int c = q * 16 + 2 * j + u;
      const float* xc = xb + (size_t)c * 4096 + h * 64 + w;
      float v0 = hm ? xc[-64] : 0.f;
      float v1 = xc[0];
      float v2 = hp ? xc[64] : 0.f;
      const float* wp = dw_w + c * 9;                     // wave-uniform
      float a = dw_b[c];
      #pragma unroll
      for (int dh = 0; dh < 3; ++dh) {
        float v = (dh == 0) ? v0 : (dh == 1) ? v1 : v2;
        float vm = __shfl(v, w - 1, 64);
        float vp = __shfl(v, w + 1, 64);
        if (w == 0)  vm = 0.f;
        if (w == 63) vp = 0.f;
        a = fmaf(vm, wp[dh * 3 + 0], a);
        a = fmaf(v,  wp[dh * 3 + 1], a);
        a = fmaf(vp, wp[dh * 3 + 2], a);
      }
      s1 += a;
      s2 = fmaf(a, a, s2);
      av[2 * j + u] = a;
    }
  }

  psq[q * 64 + w] = s1;
  psq[1024 + q * 64 + w] = s2;
  __syncthreads();
  if (t < 64) {
    float a = 0.f, b = 0.f;
    #pragma unroll
    for (int j = 0; j < 16; ++j) { a += psq[j * 64 + t]; b += psq[1024 + j * 64 + t]; }
    float mu = a * (1.f / 256.f);
    murs[t] = mu;
    murs[64 + t] = rsqrtf(b * (1.f / 256.f) - mu * mu + 1e-5f);
  }
  __syncthreads();
  {                                          // LN + GELU on fp32 regs -> x1t bf16
    float mu = murs[w], rs = murs[64 + w];
    #pragma unroll
    for (int j = 0; j < 8; ++j) {
      int c = q * 16 + 2 * j;
      float y0 = fmaf((av[2 * j] - mu) * rs, ln_g[c], ln_b[c]);
      float y1 = fmaf((av[2 * j + 1] - mu) * rs, ln_g[c + 1], ln_b[c + 1]);
      float g0 = 0.5f * y0 * (1.f + erff(y0 * 0.70710678f));
      float g1 = 0.5f * y1 * (1.f + erff(y1 * 0.70710678f));
      *(unsigned*)&x1t[w * 264 + c] = (unsigned)f2bf(g0) | ((unsigned)f2bf(g1) << 16);
    }
  }
  __syncthreads();

  // coalesced x1 write: 64 px x 32 chunks of 16B
  const size_t pix0 = (size_t)n4 * 4096 + (size_t)h * 64;
  #pragma unroll
  for (int r = 0; r < 2; ++r) {
    int j = t + r * 1024;
    int px = j >> 5, cu = j & 31;
    *(uint4*)&x1g[(pix0 + px) * 256 + cu * 8] = *(const uint4*)&x1t[px * 264 + cu * 8];
  }
}

// ---------------- K3: x1 tile -> OM GEMM -> sampling -> out-proj -> NCHW ----
// 512 blocks x 512 thr (32 px each). Som never leaves LDS.
__global__ __launch_bounds__(512) void fused_so_k(
    const __hip_bfloat16* __restrict__ x1g, const __hip_bfloat16* __restrict__ xpu,
    const __hip_bfloat16* __restrict__ BtOM, const float* __restrict__ bOM,
    const __hip_bfloat16* __restrict__ BtO, const float* __restrict__ out_b,
    float* __restrict__ out)
{
  __shared__ __align__(16) char smem[78336];
  unsigned short* x1s = (unsigned short*)smem;            // [32][256] 16384 B
  unsigned short* st  = (unsigned short*)smem;            // [32][264] 16896 B (x1s dead)
  unsigned short* Som = (unsigned short*)(smem + 16896);  // [32][448] 28672 B (Bom buf0 dead)
  // Bom dbuf: 16896 + buf*28672 ; BtO dbuf: 45568 + buf*16384 (Bom buf1 dead)

  const int bid = blockIdx.x;                             // 512
  const int swz = ((bid & 7) << 6) | (bid >> 3);          // bijective XCD swizzle
  const int pix0 = swz << 5;                              // 32 consecutive pixels
  const int t = threadIdx.x;

  const int wave = t >> 6, lane = t & 63;
  const int quad = lane >> 4, lr = lane & 15;
  const int wm = wave >> 2, wn = wave & 3;                // wm 0..1, wn 0..3

  auto stageB = [&](int s, int buf) {                     // BtOM [448][32] = 1792 x 16B
    char* dst = smem + 16896 + buf * 28672;
    #pragma unroll
    for (int r = 0; r < 3; ++r) {
      int j = t + r * 512;
      int col = j >> 2, kq = j & 3;
      g2lds16(BtOM + (size_t)col * 256 + s * 32 + kq * 8, dst + j * 16);
    }
    if (t < 256) {
      int j = t + 1536;
      int col = j >> 2, kq = j & 3;
      g2lds16(BtOM + (size_t)col * 256 + s * 32 + kq * 8, dst + j * 16);
    }
  };
  auto stageO = [&](int s, int buf) {                     // BtO [256][32] = 1024 x 16B
    char* dst = smem + 45568 + buf * 16384;
    #pragma unroll
    for (int r = 0; r < 2; ++r) {
      int j = t + r * 512;
      int col = j >> 2, kq = j & 3;
      g2lds16(BtO + (size_t)col * 256 + s * 32 + kq * 8, dst + j * 16);
    }
  };

  // stage x1 tile (32 px x 32 chunks) + Bom step0
  #pragma unroll
  for (int r = 0; r < 2; ++r) {
    int j = t + r * 512;
    int px = j >> 5, cu = j & 31;
    g2lds16(x1g + (size_t)(pix0 + px) * 256 + cu * 8, smem + j * 16);
  }
  stageB(0, 0);
  __syncthreads();

  // ---- OM GEMM: M=32, N=448 (432 valid), K=256. 8 waves = 2m x 4n. ----
  bf16x8 areg[8];
  #pragma unroll
  for (int s = 0; s < 8; ++s)
    areg[s] = *(const bf16x8*)&x1s[(wm * 16 + lr) * 256 + s * 32 + quad * 8];

  f32x4 acc[7];
  #pragma unroll
  for (int i = 0; i < 7; ++i) acc[i] = (f32x4){0.f, 0.f, 0.f, 0.f};

  #pragma unroll
  for (int s = 0; s < 8; ++s) {
    if (s < 7) stageB(s + 1, (s + 1) & 1);
    const short* B = (const short*)(smem + 16896 + (s & 1) * 28672);
    bf16x8 bfr[7];
    #pragma unroll
    for (int ni = 0; ni < 7; ++ni)
      bfr[ni] = *(const bf16x8*)&B[(wn * 112 + ni * 16 + lr) * 32 + quad * 8];
    #pragma unroll
    for (int ni = 0; ni < 7; ++ni)
      acc[ni] = __builtin_amdgcn_mfma_f32_16x16x32_bf16(areg[s], bfr[ni], acc[ni], 0, 0, 0);
    __syncthreads();
  }

  // Som = OM result + bias, in LDS (cols >=432 written but never read)
  #pragma unroll
  for (int ni = 0; ni < 7; ++ni) {
    int col = wn * 112 + ni * 16 + lr;
    float bv = bOM[col];
    #pragma unroll
    for (int reg = 0; reg < 4; ++reg) {
      int m = wm * 16 + quad * 4 + reg;
      Som[m * 448 + col] = f2bf(acc[ni][reg] + bv);
    }
  }
  __syncthreads();

  stageO(0, 0);                              // hides under sampling

  // ---- sampling: thread = (pixel pl 0..31, group g 0..15) ----
  {
    const int pl = t >> 4, g = t & 15;
    const int pix = pix0 + pl;
    const int n4s = pix >> 12;
    const int hw = pix & 4095;
    const int h = hw >> 6, w = hw & 63;
    const unsigned short* omp = Som + pl * 448;

    float mk[9];
    {
      float mx = -1e30f;
      #pragma unroll
      for (int p = 0; p < 9; ++p) { mk[p] = us2f(omp[288 + g * 9 + p]); mx = fmaxf(mx, mk[p]); }
      float se = 0.f;
      #pragma unroll
      for (int p = 0; p < 9; ++p) { mk[p] = __expf(mk[p] - mx); se += mk[p]; }
      float inv = 1.f / se;
      #pragma unroll
      for (int p = 0; p < 9; ++p) mk[p] *= inv;
    }

    const __hip_bfloat16* xpg = xpu + (g << 4);
    float ax[16];
    #pragma unroll
    for (int i = 0; i < 16; ++i) ax[i] = 0.f;

    auto corner = [&](int iy, int ix, float wt) {
      if ((unsigned)(iy - 1) >= 64u || (unsigned)(ix - 1) >= 64u) return;
      const __hip_bfloat16* src =
          xpg + ((size_t)((n4s << 12) + (iy - 1) * 64 + (ix - 1)) << 8);
      uint4 u0 = *(const uint4*)src;
      uint4 u1 = *(const uint4*)(src + 8);
      const unsigned uu[8] = {u0.x, u0.y, u0.z, u0.w, u1.x, u1.y, u1.z, u1.w};
      #pragma unroll
      for (int i = 0; i < 8; ++i) {
        float lo = us2f((unsigned short)(uu[i] & 0xffff));
        float hi = us2f((unsigned short)(uu[i] >> 16));
        ax[2 * i + 0] = fmaf(wt, lo, ax[2 * i + 0]);
        ax[2 * i + 1] = fmaf(wt, hi, ax[2 * i + 1]);
      }
    };

    #pragma unroll
    for (int p = 0; p < 9; ++p) {
      float ox = us2f(omp[g * 18 + 2 * p]), oy = us2f(omp[g * 18 + 2 * p + 1]);
      float px = (float)(w + p / 3) + ox;
      float py = (float)(h + p % 3) + oy;
      float xf = floorf(px), yf = floorf(py);
      float wx = px - xf, wy = py - yf;
      int ix = (int)xf, iy = (int)yf;
      float m = mk[p];
      corner(iy,     ix,     (1.f - wy) * (1.f - wx) * m);
      corner(iy,     ix + 1, (1.f - wy) * wx * m);
      corner(iy + 1, ix,     wy * (1.f - wx) * m);
      corner(iy + 1, ix + 1, wy * wx * m);
    }

    unsigned short ub[16];
    #pragma unroll
    for (int i = 0; i < 16; ++i) ub[i] = f2bf(ax[i]);
    uint4 u0, u1;
    u0.x = (unsigned)ub[0] | ((unsigned)ub[1] << 16);
    u0.y = (unsigned)ub[2] | ((unsigned)ub[3] << 16);
    u0.z = (unsigned)ub[4] | ((unsigned)ub[5] << 16);
    u0.w = (unsigned)ub[6] | ((unsigned)ub[7] << 16);
    u1.x = (unsigned)ub[8] | ((unsigned)ub[9] << 16);
    u1.y = (unsigned)ub[10] | ((unsigned)ub[11] << 16);
    u1.z = (unsigned)ub[12] | ((unsigned)ub[13] << 16);
    u1.w = (unsigned)ub[14] | ((unsigned)ub[15] << 16);
    *(uint4*)&st[pl * 264 + g * 16] = u0;
    *(uint4*)&st[pl * 264 + g * 16 + 8] = u1;
  }
  __syncthreads();                           // st ready; stageO(0) drained

  // ---- out-proj GEMM: st(32x256) @ BtO^T. 8 waves = 2m x 4n. 2-phase. ----
  bf16x8 areg2[8];
  #pragma unroll
  for (int s = 0; s < 8; ++s)
    areg2[s] = *(const bf16x8*)&st[(wm * 16 + lr) * 264 + s * 32 + quad * 8];

  f32x4 acc2[4];
  #pragma unroll
  for (int i = 0; i < 4; ++i) acc2[i] = (f32x4){0.f, 0.f, 0.f, 0.f};

  #pragma unroll
  for (int s = 0; s < 8; ++s) {
    if (s < 7) stageO(s + 1, (s + 1) & 1);
    const short* B = (const short*)(smem + 45568 + (s & 1) * 16384);
    bf16x8 bfr[4];
    #pragma unroll
    for (int ni = 0; ni < 4; ++ni)
      bfr[ni] = *(const bf16x8*)&B[(wn * 64 + ni * 16 + lr) * 32 + quad * 8];
    #pragma unroll
    for (int ni = 0; ni < 4; ++ni)
      acc2[ni] = __builtin_amdgcn_mfma_f32_16x16x32_bf16(areg2[s], bfr[ni], acc2[ni], 0, 0, 0);
    __syncthreads();
  }

  // fp32 NCHW stores: one wave's 4 quads cover each full 64-B line
  const int n4 = pix0 >> 12, hw0 = pix0 & 4095;
  #pragma unroll
  for (int ni = 0; ni < 4; ++ni) {
    int col = wn * 64 + ni * 16 + lr;
    float bv = out_b[col];
    float4 v;
    v.x = acc2[ni][0] + bv; v.y = acc2[ni][1] + bv;
    v.z = acc2[ni][2] + bv; v.w = acc2[ni][3] + bv;
    *(float4*)&out[(size_t)(n4 * 256 + col) * 4096 + hw0 + wm * 16 + quad * 4] = v;
  }
}

extern "C" void kernel_launch(void* const* d_in, const int* in_sizes, int n_in,
                              void* d_out, int out_size, void* d_ws, size_t ws_size,
                              hipStream_t stream) {
  const float* x      = (const float*)d_in[0];
  const float* dw_w   = (const float*)d_in[1];
  const float* dw_b   = (const float*)d_in[2];
  const float* ln_g   = (const float*)d_in[3];
  const float* ln_b   = (const float*)d_in[4];
  const float* off_w  = (const float*)d_in[5];
  const float* off_b  = (const float*)d_in[6];
  const float* mask_w = (const float*)d_in[7];
  const float* mask_b = (const float*)d_in[8];
  const float* inp_w  = (const float*)d_in[9];
  const float* inp_b  = (const float*)d_in[10];
  const float* out_w  = (const float*)d_in[11];
  const float* out_b  = (const float*)d_in[12];
  float* out = (float*)d_out;

  char* w0 = (char*)d_ws;
  __hip_bfloat16* xpu  = (__hip_bfloat16*)(w0);               //  8,388,608 B
  __hip_bfloat16* x1g  = (__hip_bfloat16*)(w0 + 8388608);     //  8,388,608 B
  __hip_bfloat16* BtI  = (__hip_bfloat16*)(w0 + 16777216);    //    131,072 B
  __hip_bfloat16* BtOM = (__hip_bfloat16*)(w0 + 16908288);    //    262,144 B
  __hip_bfloat16* BtO  = (__hip_bfloat16*)(w0 + 17170432);    //    131,072 B
  float*          bOM  = (float*)(w0 + 17301504);             //      2,048 B
  if (ws_size < 17303552) return;

  prep_w_k<<<1024, 256, 0, stream>>>(inp_w, off_w, off_b, mask_w, mask_b,
                                     out_w, BtI, BtOM, BtO, bOM);
  stage2_gi_k<<<512, 1024, 0, stream>>>(x, dw_w, dw_b, ln_g, ln_b,
                                        BtI, inp_b, xpu, x1g);
  fused_so_k<<<512, 512, 0, stream>>>(x1g, xpu, BtOM, bOM, BtO, out_b, out);
}